// Round 9
// baseline (1300.797 us; speedup 1.0000x reference)
//
#include <hip/hip_runtime.h>
#include <stdint.h>

// Problem constants
constexpr int NB = 4;      // batch
constexpr int NC = 256;    // channels
constexpr int HW = 64;     // spatial side
constexpr int NP = 4096;   // HW*HW
constexpr int NM = 8;      // matrices for Newton-Schulz: 2 feats x 4 batches
constexpr int NS_ITERS = 7;       // R8: lam_scaled ~0.135 -> residual 4.4e-13 at 7 (fp32 floor 6e-8)
constexpr int NSLAB = 64;         // R2: score occupancy fix
constexpr int PSLAB = NP / NSLAB; // 64
constexpr int KSPLIT = 8;         // R3: cov K-split
constexpr int KCHUNK = NP / KSPLIT; // 512

// R6: fp16 Markidis split (bf16 2-split score error ~1e-5 caused argmax flips, R5).
// Pre-scale by 512 so lo stays out of fp16-subnormal range; uniform 512^2 scaling
// of D is argmax-invariant (D only feeds score/argmax).
constexpr float SPLIT_SCALE = 512.0f;

typedef __attribute__((ext_vector_type(8))) _Float16 h8v;  // 8 fp16 (4 VGPRs)
typedef __attribute__((ext_vector_type(4))) float f4v;     // MFMA acc

// async global->LDS, 16B per lane; lds arg must be wave-uniform
#define GLD16(lds, g)                                                        \
  __builtin_amdgcn_global_load_lds(                                          \
      (const __attribute__((address_space(1))) void*)(g),                    \
      (__attribute__((address_space(3))) void*)(lds), 16, 0, 0)

// ---------------------------------------------------------------------------
// 1. per-(feat,b,c) mean over P
__global__ __launch_bounds__(256) void mean_kernel(const float* __restrict__ content,
                                                   const float* __restrict__ style,
                                                   float* __restrict__ mean) {
  int id = blockIdx.x;              // [0, 2*NB*NC)
  int feat = id / (NB * NC);
  int bc = id % (NB * NC);
  const float* src = (feat ? style : content) + (size_t)bc * NP;
  float s = 0.f;
  for (int i = threadIdx.x; i < NP; i += 256) s += src[i];
  __shared__ float red[256];
  red[threadIdx.x] = s;
  __syncthreads();
  for (int st = 128; st > 0; st >>= 1) {
    if (threadIdx.x < st) red[threadIdx.x] += red[threadIdx.x + st];
    __syncthreads();
  }
  if (threadIdx.x == 0) mean[id] = red[0] * (1.0f / NP);
}

// ---------------------------------------------------------------------------
// 1b. R9: fused mean-subtract + transpose: ZT[m][p][c] = src[m][c][p] - mu[c].
//     One-time 64MB traffic so cov staging needs NO transposed LDS writes
//     (R7/R8: transpose staging was the 3.9M->6.5M bank-conflict source).
__global__ __launch_bounds__(256) void zt_kernel(const float* __restrict__ content,
                                                 const float* __restrict__ style,
                                                 const float* __restrict__ mean,
                                                 float* __restrict__ ZT) {
  int m = blockIdx.z; int feat = m >> 2, b = m & 3;
  const float* src = (feat ? style : content) + (size_t)b * NC * NP;
  const float* mu = mean + (size_t)feat * NB * NC + b * NC;
  float* dst = ZT + (size_t)m * NP * NC;
  int p0 = blockIdx.x * 32, c0 = blockIdx.y * 32;
  __shared__ float tt[32][33];
  int tid = threadIdx.x;
  for (int idx = tid; idx < 1024; idx += 256) {
    int r = idx >> 5, cc = idx & 31;   // r: c-row, cc: p-col
    tt[r][cc] = src[(size_t)(c0 + r) * NP + p0 + cc] - mu[c0 + r];
  }
  __syncthreads();
  for (int idx = tid; idx < 1024; idx += 256) {
    int r = idx >> 5, cc = idx & 31;   // r: p-row, cc: c-col
    dst[(size_t)(p0 + r) * NC + c0 + cc] = tt[cc][r];
  }
}

// ---------------------------------------------------------------------------
// 2. R9 rewrite: pcov from ZT[p][c] rows. Staging = direct float4 row copies
//    (coalesced global, b128 LDS writes 2-way/free — whiten-proven pattern);
//    compute reads b128 (As broadcast, Bs 2-way/free). Same fp32x32->fp64
//    accumulation as R8 (bit-identical math). Upper-tri tiles, K-split 8.
__global__ __launch_bounds__(256) void cov_kernel(const float* __restrict__ ZT,
                                                  double* __restrict__ pcov) {
  int m = blockIdx.z;
  const float* Z = ZT + (size_t)m * NP * NC;   // [p][c]
  int t = blockIdx.x, ti = 0, rem = t;
  while (rem >= 4 - ti) { rem -= 4 - ti; ti++; }
  int tj = ti + rem;
  int i0 = ti * 64, j0 = tj * 64;
  int p0 = blockIdx.y * KCHUNK;
  __shared__ float As[32][68];   // [p][i-chan], 272B rows (17*16B): b128-aligned
  __shared__ float Bs[32][68];   // [p][j-chan]
  int tid = threadIdx.x, tx = tid & 15, ty = tid >> 4;
  double acc[4][4] = {};
  for (int c0 = 0; c0 < KCHUNK; c0 += 32) {
    for (int idx = tid; idx < 512; idx += 256) {
      int pp = idx >> 4, f4 = (idx & 15) * 4;
      const float* zr = Z + (size_t)(p0 + c0 + pp) * NC;
      *(float4*)&As[pp][f4] = *(const float4*)&zr[i0 + f4];
      *(float4*)&Bs[pp][f4] = *(const float4*)&zr[j0 + f4];
    }
    __syncthreads();
    float f[4][4] = {};
#pragma unroll
    for (int kk = 0; kk < 32; kk++) {
      float4 av = *(const float4*)&As[kk][ty * 4];
      float4 bv = *(const float4*)&Bs[kk][tx * 4];
      float a[4] = {av.x, av.y, av.z, av.w};
      float bb[4] = {bv.x, bv.y, bv.z, bv.w};
#pragma unroll
      for (int i = 0; i < 4; i++)
#pragma unroll
        for (int j = 0; j < 4; j++) f[i][j] += a[i] * bb[j];
    }
#pragma unroll
    for (int i = 0; i < 4; i++)
#pragma unroll
      for (int j = 0; j < 4; j++) acc[i][j] += (double)f[i][j];
    __syncthreads();
  }
  double* dst = pcov + ((size_t)blockIdx.y * NM + m) * NC * NC;
#pragma unroll
  for (int i = 0; i < 4; i++)
#pragma unroll
    for (int j = 0; j < 4; j++)
      dst[(size_t)(i0 + ty * 4 + i) * NC + j0 + tx * 4 + j] = acc[i][j];
}

// 2b. sum K-split partials; mirror lower triangle from upper tiles
__global__ __launch_bounds__(256) void cov_reduce_kernel(const double* __restrict__ pcov,
                                                         double* __restrict__ cov) {
  size_t idx = (size_t)blockIdx.x * 256 + threadIdx.x;  // [0, NM*NC*NC)
  int m = (int)(idx >> 16);
  int ij = (int)(idx & 65535);
  int i = ij >> 8, j = ij & 255;
  int src = ((i >> 6) <= (j >> 6)) ? ij : ((j << 8) | i);
  double s = 0;
  for (int k = 0; k < KSPLIT; k++)
    s += pcov[((size_t)k * NM + m) * 65536 + src];
  cov[idx] = s;
}

// ---------------------------------------------------------------------------
// 3. Gershgorin bound (abs row sum, A symmetric); init Y = s*A, Z = I
__global__ __launch_bounds__(256) void bound_init_kernel(const double* __restrict__ cov,
                                                         double* __restrict__ Y,
                                                         double* __restrict__ Z,
                                                         double* __restrict__ scaleArr) {
  int m = blockIdx.x;
  const double* A = cov + (size_t)m * NC * NC;
  int t = threadIdx.x;
  double s = 0;
  for (int i = 0; i < NC; i++) s += fabs(A[(size_t)i * NC + t]);   // coalesced
  __shared__ double red[256];
  red[t] = s;
  __syncthreads();
  for (int st = 128; st > 0; st >>= 1) {
    if (t < st) red[t] = fmax(red[t], red[t + st]);
    __syncthreads();
  }
  double scale = 1.0 / red[0];     // lam_max <= max abs row sum (rigorous upper bound)
  if (t == 0) scaleArr[m] = scale;
  double* Ym = Y + (size_t)m * NC * NC;
  double* Zm = Z + (size_t)m * NC * NC;
  for (int idx = t; idx < NC * NC; idx += 256) {
    Ym[idx] = A[idx] * scale;
    Zm[idx] = ((idx / NC) == (idx % NC)) ? 1.0 : 0.0;
  }
}

// ---------------------------------------------------------------------------
// 4a. T = Z * Y (fp64, 32x32 tiles, 2x2 micro)
__global__ __launch_bounds__(256) void ns_t_kernel(const double* __restrict__ Zin,
                                                   const double* __restrict__ Yin,
                                                   double* __restrict__ T) {
  int m = blockIdx.z;
  const double* Am = Zin + (size_t)m * NC * NC;
  const double* Bm = Yin + (size_t)m * NC * NC;
  double* Tm = T + (size_t)m * NC * NC;
  __shared__ double As[32][33];
  __shared__ double Bs[32][33];
  int tid = threadIdx.x, tx = tid & 15, ty = tid >> 4;
  int i0 = blockIdx.x * 32, j0 = blockIdx.y * 32;
  double a00 = 0, a01 = 0, a10 = 0, a11 = 0;
  for (int k0 = 0; k0 < NC; k0 += 32) {
    for (int idx = tid; idx < 1024; idx += 256) {
      int r = idx >> 5, cc = idx & 31;
      As[r][cc] = Am[(size_t)(i0 + r) * NC + k0 + cc];
      Bs[r][cc] = Bm[(size_t)(k0 + r) * NC + j0 + cc];
    }
    __syncthreads();
#pragma unroll
    for (int kk = 0; kk < 32; kk++) {
      double x0 = As[ty * 2][kk], x1 = As[ty * 2 + 1][kk];
      double y0 = Bs[kk][tx * 2], y1 = Bs[kk][tx * 2 + 1];
      a00 += x0 * y0; a01 += x0 * y1; a10 += x1 * y0; a11 += x1 * y1;
    }
    __syncthreads();
  }
  Tm[(size_t)(i0 + ty * 2) * NC + j0 + tx * 2] = a00;
  Tm[(size_t)(i0 + ty * 2) * NC + j0 + tx * 2 + 1] = a01;
  Tm[(size_t)(i0 + ty * 2 + 1) * NC + j0 + tx * 2] = a10;
  Tm[(size_t)(i0 + ty * 2 + 1) * NC + j0 + tx * 2 + 1] = a11;
}

// 4b. Yout = 1.5*Yin - 0.5*Yin*T ; Zout = 1.5*Zin - 0.5*T*Zin
__global__ __launch_bounds__(256) void ns_upd_kernel(const double* __restrict__ Yin,
                                                     const double* __restrict__ Zin,
                                                     const double* __restrict__ T,
                                                     double* __restrict__ Yout,
                                                     double* __restrict__ Zout) {
  int z = blockIdx.z;
  int m = z & 7, which = z >> 3;
  size_t off = (size_t)m * NC * NC;
  const double* Am = which == 0 ? (Yin + off) : (T + off);
  const double* Bm = which == 0 ? (T + off) : (Zin + off);
  const double* Sm = which == 0 ? (Yin + off) : (Zin + off);
  double* Om = which == 0 ? (Yout + off) : (Zout + off);
  __shared__ double As[32][33];
  __shared__ double Bs[32][33];
  int tid = threadIdx.x, tx = tid & 15, ty = tid >> 4;
  int i0 = blockIdx.x * 32, j0 = blockIdx.y * 32;
  double a00 = 0, a01 = 0, a10 = 0, a11 = 0;
  for (int k0 = 0; k0 < NC; k0 += 32) {
    for (int idx = tid; idx < 1024; idx += 256) {
      int r = idx >> 5, cc = idx & 31;
      As[r][cc] = Am[(size_t)(i0 + r) * NC + k0 + cc];
      Bs[r][cc] = Bm[(size_t)(k0 + r) * NC + j0 + cc];
    }
    __syncthreads();
#pragma unroll
    for (int kk = 0; kk < 32; kk++) {
      double x0 = As[ty * 2][kk], x1 = As[ty * 2 + 1][kk];
      double y0 = Bs[kk][tx * 2], y1 = Bs[kk][tx * 2 + 1];
      a00 += x0 * y0; a01 += x0 * y1; a10 += x1 * y0; a11 += x1 * y1;
    }
    __syncthreads();
  }
  int r0 = i0 + ty * 2, c0 = j0 + tx * 2;
  Om[(size_t)r0 * NC + c0] = 1.5 * Sm[(size_t)r0 * NC + c0] - 0.5 * a00;
  Om[(size_t)r0 * NC + c0 + 1] = 1.5 * Sm[(size_t)r0 * NC + c0 + 1] - 0.5 * a01;
  Om[(size_t)(r0 + 1) * NC + c0] = 1.5 * Sm[(size_t)(r0 + 1) * NC + c0] - 0.5 * a10;
  Om[(size_t)(r0 + 1) * NC + c0 + 1] = 1.5 * Sm[(size_t)(r0 + 1) * NC + c0 + 1] - 0.5 * a11;
}

// ---------------------------------------------------------------------------
// 5. finalize: inv_c = Z_c*sqrt(s), inv_s = Z_s*sqrt(s), sqr_s = Y_s/sqrt(s)  (fp32)
__global__ __launch_bounds__(256) void finalize_kernel(const double* __restrict__ Yf,
                                                       const double* __restrict__ Zf,
                                                       const double* __restrict__ scaleArr,
                                                       float* __restrict__ inv_c,
                                                       float* __restrict__ inv_s,
                                                       float* __restrict__ sqr_s) {
  int which = blockIdx.y;
  int idx = blockIdx.x * 256 + threadIdx.x;   // [0, NB*NC*NC)
  int b = idx >> 16;
  int ij = idx & 65535;
  if (which == 0) {
    double s = sqrt(scaleArr[b]);
    inv_c[idx] = (float)(Zf[(size_t)b * 65536 + ij] * s);
  } else if (which == 1) {
    double s = sqrt(scaleArr[4 + b]);
    inv_s[idx] = (float)(Zf[(size_t)(4 + b) * 65536 + ij] * s);
  } else {
    double s = sqrt(scaleArr[4 + b]);
    sqr_s[idx] = (float)(Yf[(size_t)(4 + b) * 65536 + ij] / s);
  }
}

// ---------------------------------------------------------------------------
// 6. whitening: dst[c][x] = sum_k M[c][k]*(src[k][x]-mu[k]). M symmetric ->
//    stage Ms[k][c] from M rows (float4, conflict-free). 128x64 tile, 4x8 micro.
__global__ __launch_bounds__(256) void whiten_kernel(const float* __restrict__ content,
                                                     const float* __restrict__ style,
                                                     const float* __restrict__ mean,
                                                     const float* __restrict__ inv_c,
                                                     const float* __restrict__ inv_s,
                                                     float* __restrict__ ncw,
                                                     float* __restrict__ nsw) {
  int z = blockIdx.z; int feat = z >> 2, b = z & 3;
  const float* src = (feat ? style : content) + (size_t)b * NC * NP;
  const float* mu = mean + (size_t)feat * NB * NC + b * NC;
  const float* M = (feat ? inv_s : inv_c) + (size_t)b * NC * NC;
  float* dst = (feat ? nsw : ncw) + (size_t)b * NC * NP;
  int x0 = blockIdx.x * 128, c0 = blockIdx.y * 64;
  __shared__ float Ms[32][68];    // [k][c], 272B rows (17*16B aligned)
  __shared__ float Xs[32][136];   // [k][x], 544B rows (34*16B aligned)
  int tid = threadIdx.x, tx = tid & 15, ty = tid >> 4;
  float acc[4][8] = {};   // [c_i][x_j]: j0..3 -> x0+tx*4, j4..7 -> x0+64+tx*4
  for (int k0 = 0; k0 < NC; k0 += 32) {
    for (int idx = tid; idx < 512; idx += 256) {
      int kk = idx >> 4, r4 = (idx & 15) * 4;
      *(float4*)&Ms[kk][r4] = *(const float4*)&M[(size_t)(k0 + kk) * NC + c0 + r4];
    }
    for (int idx = tid; idx < 1024; idx += 256) {
      int r = idx >> 5, c4 = (idx & 31) * 4;
      float4 v = *(const float4*)&src[(size_t)(k0 + r) * NP + x0 + c4];
      float mm = mu[k0 + r];
      v.x -= mm; v.y -= mm; v.z -= mm; v.w -= mm;
      *(float4*)&Xs[r][c4] = v;
    }
    __syncthreads();
#pragma unroll
    for (int kk = 0; kk < 32; kk++) {
      float4 av = *(const float4*)&Ms[kk][ty * 4];
      float4 b0 = *(const float4*)&Xs[kk][tx * 4];
      float4 b1 = *(const float4*)&Xs[kk][64 + tx * 4];
      float a[4] = {av.x, av.y, av.z, av.w};
      float bb[8] = {b0.x, b0.y, b0.z, b0.w, b1.x, b1.y, b1.z, b1.w};
#pragma unroll
      for (int i = 0; i < 4; i++)
#pragma unroll
        for (int j = 0; j < 8; j++) acc[i][j] += a[i] * bb[j];
    }
    __syncthreads();
  }
#pragma unroll
  for (int i = 0; i < 4; i++) {
    *(float4*)&dst[(size_t)(c0 + ty * 4 + i) * NP + x0 + tx * 4] =
        make_float4(acc[i][0], acc[i][1], acc[i][2], acc[i][3]);
    *(float4*)&dst[(size_t)(c0 + ty * 4 + i) * NP + x0 + 64 + tx * 4] =
        make_float4(acc[i][4], acc[i][5], acc[i][6], acc[i][7]);
  }
}

// ---------------------------------------------------------------------------
// 7. per-position channel sum-of-squares, then 1/knorm via 3x3 clipped box
__global__ __launch_bounds__(256) void ssq_kernel(const float* __restrict__ nsw,
                                                  float* __restrict__ ssq) {
  int idx = blockIdx.x * 256 + threadIdx.x;  // b*NP+y
  int b = idx >> 12, y = idx & 4095;
  const float* f = nsw + (size_t)b * NC * NP + y;
  float s = 0.f;
  for (int c = 0; c < NC; c++) {
    float v = f[(size_t)c * NP];
    s += v * v;
  }
  ssq[idx] = s;
}

__global__ __launch_bounds__(256) void rknorm_kernel(const float* __restrict__ ssq,
                                                     float* __restrict__ rk) {
  int idx = blockIdx.x * 256 + threadIdx.x;
  int b = idx >> 12, p = idx & 4095;
  int pi = p >> 6, pj = p & 63;
  float s = 0.f;
#pragma unroll
  for (int d = -1; d <= 1; d++)
#pragma unroll
    for (int e = -1; e <= 1; e++) {
      if ((unsigned)(pi + d) < 64u && (unsigned)(pj + e) < 64u)
        s += ssq[b * NP + (pi + d) * 64 + pj + e];
    }
  rk[idx] = 1.0f / sqrtf(s);
}

// ---------------------------------------------------------------------------
// 7b. transpose + fp16 Markidis split: [c][p] fp32 -> [p][c] (hi, lo) fp16,
//     pre-scaled by SPLIT_SCALE (argmax-invariant).
__global__ __launch_bounds__(256) void split_kernel(const float* __restrict__ ncw,
                                                    const float* __restrict__ nsw,
                                                    _Float16* __restrict__ BhiT,
                                                    _Float16* __restrict__ BloT,
                                                    _Float16* __restrict__ AhiT,
                                                    _Float16* __restrict__ AloT) {
  int z = blockIdx.z; int feat = z >> 2, b = z & 3;
  const float* src = (feat ? nsw : ncw) + (size_t)b * NC * NP;
  _Float16* oh = (feat ? AhiT : BhiT) + (size_t)b * NP * NC;
  _Float16* ol = (feat ? AloT : BloT) + (size_t)b * NP * NC;
  int p0 = blockIdx.x * 32, c0 = blockIdx.y * 32;
  __shared__ float tt[32][33];
  int tid = threadIdx.x;
  for (int idx = tid; idx < 1024; idx += 256) {
    int r = idx >> 5, cc = idx & 31;   // r: c-row, cc: p-col
    tt[r][cc] = src[(size_t)(c0 + r) * NP + p0 + cc];
  }
  __syncthreads();
  for (int idx = tid; idx < 1024; idx += 256) {
    int r = idx >> 5, cc = idx & 31;   // r: p-row, cc: c-col
    float v = tt[cc][r] * SPLIT_SCALE;
    _Float16 h = (_Float16)v;          // v_cvt_f16_f32, RTN
    _Float16 l = (_Float16)(v - (float)h);
    size_t off = (size_t)(p0 + r) * NC + c0 + cc;
    oh[off] = h;
    ol[off] = l;
  }
}

// ---------------------------------------------------------------------------
// 8. MFMA: D[p][x] = sum_c A[p][c]*B[x][c] via 3-term fp16 split (hh, hl, lh).
//    128x128 tile/block, 4 waves each 64x64 (4x4 of mfma_f32_16x16x32_f16),
//    BK=32, global_load_lds 16B staging.
__global__ __launch_bounds__(256) void dmat_kernel(const _Float16* __restrict__ AhiT,
                                                   const _Float16* __restrict__ AloT,
                                                   const _Float16* __restrict__ BhiT,
                                                   const _Float16* __restrict__ BloT,
                                                   float* __restrict__ D, int b) {
  __shared__ _Float16 sAh[128 * 32], sAl[128 * 32], sBh[128 * 32], sBl[128 * 32];
  const _Float16* Ah = AhiT + (size_t)b * NP * NC;
  const _Float16* Al = AloT + (size_t)b * NP * NC;
  const _Float16* Bh = BhiT + (size_t)b * NP * NC;
  const _Float16* Bl = BloT + (size_t)b * NP * NC;
  int p0 = blockIdx.x * 128, x0 = blockIdx.y * 128;
  int tid = threadIdx.x, lane = tid & 63;
  int m = lane & 15, quad = lane >> 4;
  int w = tid >> 6, qr = w & 1, qc = w >> 1;
  f4v acc[4][4] = {};
  for (int step = 0; step < NC / 32; step++) {
    int c0 = step * 32;
    __syncthreads();
#pragma unroll
    for (int i = 0; i < 2; i++) {
      int seg = i * 256 + tid;
      int row = seg >> 2, koff = (seg & 3) * 8;
      int sbase = (i * 256 + (tid & ~63)) * 8;   // wave-uniform
      GLD16(&sAh[sbase], Ah + (size_t)(p0 + row) * NC + c0 + koff);
      GLD16(&sAl[sbase], Al + (size_t)(p0 + row) * NC + c0 + koff);
      GLD16(&sBh[sbase], Bh + (size_t)(x0 + row) * NC + c0 + koff);
      GLD16(&sBl[sbase], Bl + (size_t)(x0 + row) * NC + c0 + koff);
    }
    __syncthreads();   // drains vmcnt (global_load_lds) per barrier semantics
    h8v afh[4], afl[4], bfh[4], bfl[4];
#pragma unroll
    for (int t = 0; t < 4; t++) {
      int ra = (qr * 64 + t * 16 + m) * 32 + quad * 8;
      afh[t] = *(const h8v*)&sAh[ra];
      afl[t] = *(const h8v*)&sAl[ra];
      int rb = (qc * 64 + t * 16 + m) * 32 + quad * 8;
      bfh[t] = *(const h8v*)&sBh[rb];
      bfl[t] = *(const h8v*)&sBl[rb];
    }
#pragma unroll
    for (int tr = 0; tr < 4; tr++)
#pragma unroll
      for (int tc = 0; tc < 4; tc++) {
        acc[tr][tc] = __builtin_amdgcn_mfma_f32_16x16x32_f16(afh[tr], bfh[tc], acc[tr][tc], 0, 0, 0);
        acc[tr][tc] = __builtin_amdgcn_mfma_f32_16x16x32_f16(afh[tr], bfl[tc], acc[tr][tc], 0, 0, 0);
        acc[tr][tc] = __builtin_amdgcn_mfma_f32_16x16x32_f16(afl[tr], bfh[tc], acc[tr][tc], 0, 0, 0);
      }
  }
  // C/D layout: col = lane&15, row = quad*4 + reg  [verified mapping]
#pragma unroll
  for (int tr = 0; tr < 4; tr++)
#pragma unroll
    for (int tc = 0; tc < 4; tc++)
#pragma unroll
      for (int r = 0; r < 4; r++) {
        int row = p0 + qr * 64 + tr * 16 + quad * 4 + r;
        int col = x0 + qc * 64 + tc * 16 + m;
        D[(size_t)row * NP + col] = acc[tr][tc][r];
      }
}

// ---------------------------------------------------------------------------
// 9. score[p][x] = (sum_{3x3 masked} D[p+off][x+off]) * rk[p]; partial argmax per p-slab
__global__ __launch_bounds__(256) void score_kernel(const float* __restrict__ D,
                                                    const float* __restrict__ rk,
                                                    float* __restrict__ pbest,
                                                    int* __restrict__ pidx, int b) {
  int x = blockIdx.x * 256 + threadIdx.x;
  int slab = blockIdx.y;
  int xi = x >> 6, xj = x & 63;
  const float* rkb = rk + (size_t)b * NP;
  bool xm[9];
#pragma unroll
  for (int q = 0; q < 9; q++) {
    int d = q / 3 - 1, e = q % 3 - 1;
    xm[q] = ((unsigned)(xi + d) < 64u) && ((unsigned)(xj + e) < 64u);
  }
  float best = -1e30f;
  int bi = 0;
  int p0 = slab * PSLAB;
  for (int p = p0; p < p0 + PSLAB; p++) {
    int pi = p >> 6, pj = p & 63;
    float acc = 0.f;
#pragma unroll
    for (int q = 0; q < 9; q++) {
      int d = q / 3 - 1, e = q % 3 - 1;
      int off = d * 64 + e;
      bool ok = xm[q] && ((unsigned)(pi + d) < 64u) && ((unsigned)(pj + e) < 64u);
      int row = ok ? p + off : p;
      int col = ok ? x + off : x;
      float t = D[(size_t)row * NP + col];
      acc += ok ? t : 0.f;
    }
    float s = acc * rkb[p];
    if (s > best) { best = s; bi = p; }
  }
  pbest[slab * NP + x] = best;
  pidx[slab * NP + x] = bi;
}

__global__ __launch_bounds__(256) void combine_kernel(const float* __restrict__ pbest,
                                                      const int* __restrict__ pidx,
                                                      int* __restrict__ bidx, int b) {
  int x = blockIdx.x * 256 + threadIdx.x;
  float best = pbest[x];
  int bi = pidx[x];
  for (int s = 1; s < NSLAB; s++) {
    float v = pbest[s * NP + x];
    if (v > best) { best = v; bi = pidx[s * NP + x]; }
  }
  bidx[b * NP + x] = bi;
}

// ---------------------------------------------------------------------------
// 10. transpose nsw [b][c][y] -> nsT [b][y][c]
__global__ __launch_bounds__(256) void transpose_kernel(const float* __restrict__ nsw,
                                                        float* __restrict__ nsT) {
  int b = blockIdx.z;
  int y0 = blockIdx.x * 32, c0 = blockIdx.y * 32;
  __shared__ float t[32][33];
  int tid = threadIdx.x;
  for (int idx = tid; idx < 1024; idx += 256) {
    int r = idx >> 5, cc = idx & 31;
    t[r][cc] = nsw[((size_t)b * NC + c0 + r) * NP + y0 + cc];
  }
  __syncthreads();
  for (int idx = tid; idx < 1024; idx += 256) {
    int r = idx >> 5, cc = idx & 31;
    nsT[((size_t)b * NP + y0 + r) * NC + c0 + cc] = t[cc][r];
  }
}

// ---------------------------------------------------------------------------
// 11. gather-form overlap-add reassembly, divided by deconv norm
__global__ __launch_bounds__(256) void reassemble_kernel(const float* __restrict__ nsT,
                                                         const int* __restrict__ bidx,
                                                         float* __restrict__ reass) {
  int by = blockIdx.x;       // b*NP + y
  int b = by >> 12, y = by & 4095;
  int yi = y >> 6, yj = y & 63;
  int t = threadIdx.x;       // channel
  float acc = 0.f;
#pragma unroll
  for (int oi = 0; oi < 3; oi++)
#pragma unroll
    for (int oj = 0; oj < 3; oj++) {
      int xi = yi + 1 - oi, xj = yj + 1 - oj;
      if ((unsigned)xi < 64u && (unsigned)xj < 64u) {
        int p = bidx[b * NP + xi * 64 + xj];
        int qi = (p >> 6) + oi - 1, qj = (p & 63) + oj - 1;
        if ((unsigned)qi < 64u && (unsigned)qj < 64u)
          acc += nsT[((size_t)b * NP + qi * 64 + qj) * NC + t];
      }
    }
  int cy = (yi == 0 || yi == 63) ? 2 : 3;
  int cx = (yj == 0 || yj == 63) ? 2 : 3;
  reass[((size_t)b * NP + y) * NC + t] = acc / (float)(cy * cx);
}

// ---------------------------------------------------------------------------
// 12. coloring: out[b][c][y] = sum_j sqr_s[b][c][j]*reass[b][y][j] + mean_s[b][c].
//     sqr_s symmetric -> As staged from rows (float4, conflict-free).
__global__ __launch_bounds__(256) void coloring_kernel(const float* __restrict__ sqr_s,
                                                       const float* __restrict__ reass,
                                                       const float* __restrict__ mean,
                                                       float* __restrict__ out) {
  int b = blockIdx.z;
  const float* A = sqr_s + (size_t)b * NC * NC;
  const float* Bm = reass + (size_t)b * NP * NC;
  const float* mu = mean + (size_t)NB * NC + b * NC;
  float* dst = out + (size_t)b * NC * NP;
  int c0 = blockIdx.x * 64, y0 = blockIdx.y * 64;
  __shared__ float As[32][68];   // [j][c], float4 rows
  __shared__ float Bs[32][66];   // [j][y], stride 66 transposed scalar writes
  int tid = threadIdx.x, tx = tid & 15, ty = tid >> 4;
  float acc[4][4] = {};
  for (int k0 = 0; k0 < NC; k0 += 32) {
    for (int idx = tid; idx < 512; idx += 256) {
      int kk = idx >> 4, r4 = (idx & 15) * 4;   // A symmetric: row k, cols c
      *(float4*)&As[kk][r4] = *(const float4*)&A[(size_t)(k0 + kk) * NC + c0 + r4];
    }
    for (int idx = tid; idx < 2048; idx += 256) {
      int r = idx >> 5, kk = idx & 31;
      Bs[kk][r] = Bm[(size_t)(y0 + r) * NC + k0 + kk];
    }
    __syncthreads();
#pragma unroll
    for (int kk = 0; kk < 32; kk++) {
      float4 av = *(const float4*)&As[kk][ty * 4];
      float a[4] = {av.x, av.y, av.z, av.w};
      float bb[4];
      *(float2*)&bb[0] = *(const float2*)&Bs[kk][tx * 4];
      *(float2*)&bb[2] = *(const float2*)&Bs[kk][tx * 4 + 2];
#pragma unroll
      for (int i = 0; i < 4; i++)
#pragma unroll
        for (int j = 0; j < 4; j++) acc[i][j] += a[i] * bb[j];
    }
    __syncthreads();
  }
#pragma unroll
  for (int i = 0; i < 4; i++) {
    float m = mu[c0 + ty * 4 + i];
    float4 v = make_float4(acc[i][0] + m, acc[i][1] + m, acc[i][2] + m, acc[i][3] + m);
    *(float4*)&dst[(size_t)(c0 + ty * 4 + i) * NP + y0 + tx * 4] = v;
  }
}

// ---------------------------------------------------------------------------
extern "C" void kernel_launch(void* const* d_in, const int* in_sizes, int n_in,
                              void* d_out, int out_size, void* d_ws, size_t ws_size,
                              hipStream_t stream) {
  (void)in_sizes; (void)n_in; (void)out_size; (void)ws_size;
  const float* content = (const float*)d_in[0];
  const float* style = (const float*)d_in[1];
  float* out = (float*)d_out;

  // workspace carve-up (256B aligned)
  char* w = (char*)d_ws;
  auto alloc = [&](size_t bytes) -> void* {
    void* p = (void*)w;
    w += (bytes + 255) & ~(size_t)255;
    return p;
  };
  float* mean = (float*)alloc(2 * NB * NC * sizeof(float));
  double* pcov = (double*)alloc((size_t)KSPLIT * NM * NC * NC * sizeof(double));  // 32MB
  double* cov = (double*)alloc((size_t)NM * NC * NC * sizeof(double));
  double* Y0 = (double*)alloc((size_t)NM * NC * NC * sizeof(double));
  double* Z0 = (double*)alloc((size_t)NM * NC * NC * sizeof(double));
  double* Y1 = (double*)alloc((size_t)NM * NC * NC * sizeof(double));
  double* Z1 = (double*)alloc((size_t)NM * NC * NC * sizeof(double));
  double* T = (double*)alloc((size_t)NM * NC * NC * sizeof(double));
  double* scaleArr = (double*)alloc(NM * sizeof(double));
  float* inv_c = (float*)alloc((size_t)NB * NC * NC * sizeof(float));
  float* inv_s = (float*)alloc((size_t)NB * NC * NC * sizeof(float));
  float* sqr_s = (float*)alloc((size_t)NB * NC * NC * sizeof(float));
  float* ncw = (float*)alloc((size_t)NB * NC * NP * sizeof(float));
  float* nsw = (float*)alloc((size_t)NB * NC * NP * sizeof(float));
  float* ssq = (float*)alloc((size_t)NB * NP * sizeof(float));
  float* rk = (float*)alloc((size_t)NB * NP * sizeof(float));
  float* pbest = (float*)alloc((size_t)NSLAB * NP * sizeof(float));
  int* pidx = (int*)alloc((size_t)NSLAB * NP * sizeof(int));
  int* bidx = (int*)alloc((size_t)NB * NP * sizeof(int));
  float* Dbuf = (float*)alloc((size_t)NP * NP * sizeof(float));  // 64MB, multi-overlaid:
  float* ZT = Dbuf;                                    // [0, 32MB): NM*NP*NC fp32 (dead after cov)
  float* nsT = Dbuf;                                   // [0, 16MB): written after score loop
  float* reass = Dbuf + (size_t)NB * NP * NC;          // [16MB, 32MB)
  // fp16 split arrays overlay pcov (dead after cov_reduce): 4 x 8MB = 32MB exactly
  _Float16* AhiT = (_Float16*)pcov;
  _Float16* AloT = AhiT + (size_t)NB * NP * NC;
  _Float16* BhiT = AloT + (size_t)NB * NP * NC;
  _Float16* BloT = BhiT + (size_t)NB * NP * NC;

  // 1-2: stats (R9: mean-subtracted transpose feeds a conflict-free cov syrk)
  mean_kernel<<<2 * NB * NC, 256, 0, stream>>>(content, style, mean);
  zt_kernel<<<dim3(NP / 32, NC / 32, NM), 256, 0, stream>>>(content, style, mean, ZT);
  cov_kernel<<<dim3(10, KSPLIT, NM), 256, 0, stream>>>(ZT, pcov);
  cov_reduce_kernel<<<NM * NC * NC / 256, 256, 0, stream>>>(pcov, cov);

  // 3-4: Newton-Schulz inverse/forward sqrt in fp64 (Gershgorin-scaled)
  bound_init_kernel<<<NM, 256, 0, stream>>>(cov, Y0, Z0, scaleArr);
  double *Ya = Y0, *Za = Z0, *Yb = Y1, *Zb = Z1;
  for (int it = 0; it < NS_ITERS; it++) {
    ns_t_kernel<<<dim3(8, 8, NM), 256, 0, stream>>>(Za, Ya, T);
    ns_upd_kernel<<<dim3(8, 8, NM * 2), 256, 0, stream>>>(Ya, Za, T, Yb, Zb);
    double* tmp;
    tmp = Ya; Ya = Yb; Yb = tmp;
    tmp = Za; Za = Zb; Zb = tmp;
  }
  finalize_kernel<<<dim3(NB * NC * NC / 256, 3), 256, 0, stream>>>(Ya, Za, scaleArr,
                                                                   inv_c, inv_s, sqr_s);

  // 6: whiten both features (128x64 tiles)
  whiten_kernel<<<dim3(NP / 128, NC / 64, 2 * NB), 256, 0, stream>>>(
      content, style, mean, inv_c, inv_s, ncw, nsw);

  // 7: patch norms + fp16 split/transpose (split overlays pcov, dead by now)
  ssq_kernel<<<NB * NP / 256, 256, 0, stream>>>(nsw, ssq);
  rknorm_kernel<<<NB * NP / 256, 256, 0, stream>>>(ssq, rk);
  split_kernel<<<dim3(NP / 32, NC / 32, 2 * NB), 256, 0, stream>>>(ncw, nsw,
                                                                   BhiT, BloT, AhiT, AloT);

  // 8-9: per batch: D = A B^T (MFMA fp16 3-term), then shifted-sum score + argmax
  for (int b = 0; b < NB; b++) {
    dmat_kernel<<<dim3(NP / 128, NP / 128), 256, 0, stream>>>(AhiT, AloT, BhiT, BloT, Dbuf, b);
    score_kernel<<<dim3(NP / 256, NSLAB), 256, 0, stream>>>(Dbuf, rk, pbest, pidx, b);
    combine_kernel<<<NP / 256, 256, 0, stream>>>(pbest, pidx, bidx, b);
  }

  // 10-11: reassembly (gather form)
  transpose_kernel<<<dim3(NP / 32, NC / 32, NB), 256, 0, stream>>>(nsw, nsT);
  reassemble_kernel<<<NB * NP, 256, 0, stream>>>(nsT, bidx, reass);

  // 12: coloring straight into d_out (style_strength == 1.0)
  coloring_kernel<<<dim3(NC / 64, NP / 64, NB), 256, 0, stream>>>(sqr_s, reass, mean, out);
}

// Round 10
// 1267.629 us; speedup vs baseline: 1.0262x; 1.0262x over previous
//
#include <hip/hip_runtime.h>
#include <stdint.h>

// Problem constants
constexpr int NB = 4;      // batch
constexpr int NC = 256;    // channels
constexpr int HW = 64;     // spatial side
constexpr int NP = 4096;   // HW*HW
constexpr int NM = 8;      // matrices for Newton-Schulz: 2 feats x 4 batches
constexpr int NS_ITERS = 7;       // lam_scaled ~0.135 -> residual 4.4e-13 at 7 (fp32 floor 6e-8)
constexpr int NSLAB = 64;         // R2: score occupancy fix
constexpr int PSLAB = NP / NSLAB; // 64
constexpr int KSPLIT = 8;         // R3: cov K-split
constexpr int KCHUNK = NP / KSPLIT; // 512

// R6: fp16 Markidis split (bf16 2-split caused argmax flips). Pre-scale by 512
// keeps lo out of fp16-subnormal range; uniform 512^2 scaling of D is
// argmax-invariant (D only feeds score/argmax).
constexpr float SPLIT_SCALE = 512.0f;

typedef __attribute__((ext_vector_type(8))) _Float16 h8v;  // 8 fp16 (4 VGPRs)
typedef __attribute__((ext_vector_type(4))) _Float16 h4v;  // 4 fp16 (8B store)
typedef __attribute__((ext_vector_type(4))) float f4v;     // MFMA acc

// async global->LDS, 16B per lane; lds arg must be wave-uniform
#define GLD16(lds, g)                                                        \
  __builtin_amdgcn_global_load_lds(                                          \
      (const __attribute__((address_space(1))) void*)(g),                    \
      (__attribute__((address_space(3))) void*)(lds), 16, 0, 0)

// ---------------------------------------------------------------------------
// 1. per-(feat,b,c) mean over P
__global__ __launch_bounds__(256) void mean_kernel(const float* __restrict__ content,
                                                   const float* __restrict__ style,
                                                   float* __restrict__ mean) {
  int id = blockIdx.x;              // [0, 2*NB*NC)
  int feat = id / (NB * NC);
  int bc = id % (NB * NC);
  const float* src = (feat ? style : content) + (size_t)bc * NP;
  float s = 0.f;
  for (int i = threadIdx.x; i < NP; i += 256) s += src[i];
  __shared__ float red[256];
  red[threadIdx.x] = s;
  __syncthreads();
  for (int st = 128; st > 0; st >>= 1) {
    if (threadIdx.x < st) red[threadIdx.x] += red[threadIdx.x + st];
    __syncthreads();
  }
  if (threadIdx.x == 0) mean[id] = red[0] * (1.0f / NP);
}

// ---------------------------------------------------------------------------
// 2. R10: reverted to the measured-best (R7, 88us) cov: pcov partial of
//    cov = zm zm^T over K-chunk, upper-tri 64x64 tiles, transposed scalar
//    staging (stride 68) + float4 compute reads, fp32x32 -> fp64 fold.
//    (R9's ZT detour: zt transpose cost > cov gain -> net +28us; reverted.)
__global__ __launch_bounds__(256) void cov_kernel(const float* __restrict__ content,
                                                  const float* __restrict__ style,
                                                  const float* __restrict__ mean,
                                                  double* __restrict__ pcov) {
  int m = blockIdx.z; int feat = m >> 2, b = m & 3;
  const float* src = (feat ? style : content) + (size_t)b * NC * NP;
  const float* mu = mean + (size_t)feat * NB * NC + b * NC;
  int t = blockIdx.x, ti = 0, rem = t;
  while (rem >= 4 - ti) { rem -= 4 - ti; ti++; }
  int tj = ti + rem;
  int i0 = ti * 64, j0 = tj * 64;
  int p0 = blockIdx.y * KCHUNK;
  __shared__ float As[32][68];
  __shared__ float Bs[32][68];
  int tid = threadIdx.x, tx = tid & 15, ty = tid >> 4;
  double acc[4][4] = {};
  for (int c0 = 0; c0 < KCHUNK; c0 += 32) {
    for (int idx = tid; idx < 2048; idx += 256) {
      int r = idx >> 5, pp = idx & 31;
      As[pp][r] = src[(size_t)(i0 + r) * NP + p0 + c0 + pp] - mu[i0 + r];
      Bs[pp][r] = src[(size_t)(j0 + r) * NP + p0 + c0 + pp] - mu[j0 + r];
    }
    __syncthreads();
    float f[4][4] = {};
#pragma unroll
    for (int kk = 0; kk < 32; kk++) {
      float4 av = *(const float4*)&As[kk][ty * 4];
      float4 bv = *(const float4*)&Bs[kk][tx * 4];
      float a[4] = {av.x, av.y, av.z, av.w};
      float bb[4] = {bv.x, bv.y, bv.z, bv.w};
#pragma unroll
      for (int i = 0; i < 4; i++)
#pragma unroll
        for (int j = 0; j < 4; j++) f[i][j] += a[i] * bb[j];
    }
#pragma unroll
    for (int i = 0; i < 4; i++)
#pragma unroll
      for (int j = 0; j < 4; j++) acc[i][j] += (double)f[i][j];
    __syncthreads();
  }
  double* dst = pcov + ((size_t)blockIdx.y * NM + m) * NC * NC;
#pragma unroll
  for (int i = 0; i < 4; i++)
#pragma unroll
    for (int j = 0; j < 4; j++)
      dst[(size_t)(i0 + ty * 4 + i) * NC + j0 + tx * 4 + j] = acc[i][j];
}

// 2b. sum K-split partials; mirror lower triangle from upper tiles
__global__ __launch_bounds__(256) void cov_reduce_kernel(const double* __restrict__ pcov,
                                                         double* __restrict__ cov) {
  size_t idx = (size_t)blockIdx.x * 256 + threadIdx.x;  // [0, NM*NC*NC)
  int m = (int)(idx >> 16);
  int ij = (int)(idx & 65535);
  int i = ij >> 8, j = ij & 255;
  int src = ((i >> 6) <= (j >> 6)) ? ij : ((j << 8) | i);
  double s = 0;
  for (int k = 0; k < KSPLIT; k++)
    s += pcov[((size_t)k * NM + m) * 65536 + src];
  cov[idx] = s;
}

// ---------------------------------------------------------------------------
// 3. Gershgorin bound (abs row sum, A symmetric); init Y = s*A, Z = I
__global__ __launch_bounds__(256) void bound_init_kernel(const double* __restrict__ cov,
                                                         double* __restrict__ Y,
                                                         double* __restrict__ Z,
                                                         double* __restrict__ scaleArr) {
  int m = blockIdx.x;
  const double* A = cov + (size_t)m * NC * NC;
  int t = threadIdx.x;
  double s = 0;
  for (int i = 0; i < NC; i++) s += fabs(A[(size_t)i * NC + t]);   // coalesced
  __shared__ double red[256];
  red[t] = s;
  __syncthreads();
  for (int st = 128; st > 0; st >>= 1) {
    if (t < st) red[t] = fmax(red[t], red[t + st]);
    __syncthreads();
  }
  double scale = 1.0 / red[0];     // lam_max <= max abs row sum (rigorous upper bound)
  if (t == 0) scaleArr[m] = scale;
  double* Ym = Y + (size_t)m * NC * NC;
  double* Zm = Z + (size_t)m * NC * NC;
  for (int idx = t; idx < NC * NC; idx += 256) {
    Ym[idx] = A[idx] * scale;
    Zm[idx] = ((idx / NC) == (idx % NC)) ? 1.0 : 0.0;
  }
}

// ---------------------------------------------------------------------------
// 4a. T = Z * Y (fp64, 32x32 tiles, 2x2 micro)
__global__ __launch_bounds__(256) void ns_t_kernel(const double* __restrict__ Zin,
                                                   const double* __restrict__ Yin,
                                                   double* __restrict__ T) {
  int m = blockIdx.z;
  const double* Am = Zin + (size_t)m * NC * NC;
  const double* Bm = Yin + (size_t)m * NC * NC;
  double* Tm = T + (size_t)m * NC * NC;
  __shared__ double As[32][33];
  __shared__ double Bs[32][33];
  int tid = threadIdx.x, tx = tid & 15, ty = tid >> 4;
  int i0 = blockIdx.x * 32, j0 = blockIdx.y * 32;
  double a00 = 0, a01 = 0, a10 = 0, a11 = 0;
  for (int k0 = 0; k0 < NC; k0 += 32) {
    for (int idx = tid; idx < 1024; idx += 256) {
      int r = idx >> 5, cc = idx & 31;
      As[r][cc] = Am[(size_t)(i0 + r) * NC + k0 + cc];
      Bs[r][cc] = Bm[(size_t)(k0 + r) * NC + j0 + cc];
    }
    __syncthreads();
#pragma unroll
    for (int kk = 0; kk < 32; kk++) {
      double x0 = As[ty * 2][kk], x1 = As[ty * 2 + 1][kk];
      double y0 = Bs[kk][tx * 2], y1 = Bs[kk][tx * 2 + 1];
      a00 += x0 * y0; a01 += x0 * y1; a10 += x1 * y0; a11 += x1 * y1;
    }
    __syncthreads();
  }
  Tm[(size_t)(i0 + ty * 2) * NC + j0 + tx * 2] = a00;
  Tm[(size_t)(i0 + ty * 2) * NC + j0 + tx * 2 + 1] = a01;
  Tm[(size_t)(i0 + ty * 2 + 1) * NC + j0 + tx * 2] = a10;
  Tm[(size_t)(i0 + ty * 2 + 1) * NC + j0 + tx * 2 + 1] = a11;
}

// 4b. Yout = 1.5*Yin - 0.5*Yin*T ; Zout = 1.5*Zin - 0.5*T*Zin
__global__ __launch_bounds__(256) void ns_upd_kernel(const double* __restrict__ Yin,
                                                     const double* __restrict__ Zin,
                                                     const double* __restrict__ T,
                                                     double* __restrict__ Yout,
                                                     double* __restrict__ Zout) {
  int z = blockIdx.z;
  int m = z & 7, which = z >> 3;
  size_t off = (size_t)m * NC * NC;
  const double* Am = which == 0 ? (Yin + off) : (T + off);
  const double* Bm = which == 0 ? (T + off) : (Zin + off);
  const double* Sm = which == 0 ? (Yin + off) : (Zin + off);
  double* Om = which == 0 ? (Yout + off) : (Zout + off);
  __shared__ double As[32][33];
  __shared__ double Bs[32][33];
  int tid = threadIdx.x, tx = tid & 15, ty = tid >> 4;
  int i0 = blockIdx.x * 32, j0 = blockIdx.y * 32;
  double a00 = 0, a01 = 0, a10 = 0, a11 = 0;
  for (int k0 = 0; k0 < NC; k0 += 32) {
    for (int idx = tid; idx < 1024; idx += 256) {
      int r = idx >> 5, cc = idx & 31;
      As[r][cc] = Am[(size_t)(i0 + r) * NC + k0 + cc];
      Bs[r][cc] = Bm[(size_t)(k0 + r) * NC + j0 + cc];
    }
    __syncthreads();
#pragma unroll
    for (int kk = 0; kk < 32; kk++) {
      double x0 = As[ty * 2][kk], x1 = As[ty * 2 + 1][kk];
      double y0 = Bs[kk][tx * 2], y1 = Bs[kk][tx * 2 + 1];
      a00 += x0 * y0; a01 += x0 * y1; a10 += x1 * y0; a11 += x1 * y1;
    }
    __syncthreads();
  }
  int r0 = i0 + ty * 2, c0 = j0 + tx * 2;
  Om[(size_t)r0 * NC + c0] = 1.5 * Sm[(size_t)r0 * NC + c0] - 0.5 * a00;
  Om[(size_t)r0 * NC + c0 + 1] = 1.5 * Sm[(size_t)r0 * NC + c0 + 1] - 0.5 * a01;
  Om[(size_t)(r0 + 1) * NC + c0] = 1.5 * Sm[(size_t)(r0 + 1) * NC + c0] - 0.5 * a10;
  Om[(size_t)(r0 + 1) * NC + c0 + 1] = 1.5 * Sm[(size_t)(r0 + 1) * NC + c0 + 1] - 0.5 * a11;
}

// ---------------------------------------------------------------------------
// 5. finalize: inv_c = Z_c*sqrt(s), inv_s = Z_s*sqrt(s), sqr_s = Y_s/sqrt(s)  (fp32)
__global__ __launch_bounds__(256) void finalize_kernel(const double* __restrict__ Yf,
                                                       const double* __restrict__ Zf,
                                                       const double* __restrict__ scaleArr,
                                                       float* __restrict__ inv_c,
                                                       float* __restrict__ inv_s,
                                                       float* __restrict__ sqr_s) {
  int which = blockIdx.y;
  int idx = blockIdx.x * 256 + threadIdx.x;   // [0, NB*NC*NC)
  int b = idx >> 16;
  int ij = idx & 65535;
  if (which == 0) {
    double s = sqrt(scaleArr[b]);
    inv_c[idx] = (float)(Zf[(size_t)b * 65536 + ij] * s);
  } else if (which == 1) {
    double s = sqrt(scaleArr[4 + b]);
    inv_s[idx] = (float)(Zf[(size_t)(4 + b) * 65536 + ij] * s);
  } else {
    double s = sqrt(scaleArr[4 + b]);
    sqr_s[idx] = (float)(Yf[(size_t)(4 + b) * 65536 + ij] / s);
  }
}

// ---------------------------------------------------------------------------
// 6. R10 whitening: outT[x][c] = sum_k (src[k][x]-mu[k]) * M[k][c].
//    Emits [p][c] DIRECTLY (bit-identical values, stored transposed) so the
//    downstream transpose_kernel dies and split/ssq become row-wise.
//    M symmetric -> Ms[k][c] staged from M rows (float4, conflict-free).
//    128x (x) by 64c tile, 8x4 micro, float4 C-writes along c.
__global__ __launch_bounds__(256) void whiten_kernel(const float* __restrict__ content,
                                                     const float* __restrict__ style,
                                                     const float* __restrict__ mean,
                                                     const float* __restrict__ inv_c,
                                                     const float* __restrict__ inv_s,
                                                     float* __restrict__ ncwT,
                                                     float* __restrict__ nswT) {
  int z = blockIdx.z; int feat = z >> 2, b = z & 3;
  const float* src = (feat ? style : content) + (size_t)b * NC * NP;
  const float* mu = mean + (size_t)feat * NB * NC + b * NC;
  const float* M = (feat ? inv_s : inv_c) + (size_t)b * NC * NC;
  float* dst = (feat ? nswT : ncwT) + (size_t)b * NP * NC;   // [p][c]
  int x0 = blockIdx.x * 128, c0 = blockIdx.y * 64;
  __shared__ float Ms[32][68];    // [k][c]
  __shared__ float Xs[32][136];   // [k][x]
  int tid = threadIdx.x, tx = tid & 15, ty = tid >> 4;
  float acc[8][4] = {};   // [x_i][c_j]
  for (int k0 = 0; k0 < NC; k0 += 32) {
    for (int idx = tid; idx < 512; idx += 256) {
      int kk = idx >> 4, r4 = (idx & 15) * 4;
      *(float4*)&Ms[kk][r4] = *(const float4*)&M[(size_t)(k0 + kk) * NC + c0 + r4];
    }
    for (int idx = tid; idx < 1024; idx += 256) {
      int r = idx >> 5, c4 = (idx & 31) * 4;
      float4 v = *(const float4*)&src[(size_t)(k0 + r) * NP + x0 + c4];
      float mm = mu[k0 + r];
      v.x -= mm; v.y -= mm; v.z -= mm; v.w -= mm;
      *(float4*)&Xs[r][c4] = v;
    }
    __syncthreads();
#pragma unroll
    for (int kk = 0; kk < 32; kk++) {
      float4 xa = *(const float4*)&Xs[kk][ty * 8];
      float4 xb = *(const float4*)&Xs[kk][ty * 8 + 4];
      float4 mv = *(const float4*)&Ms[kk][tx * 4];
      float xv[8] = {xa.x, xa.y, xa.z, xa.w, xb.x, xb.y, xb.z, xb.w};
      float mm4[4] = {mv.x, mv.y, mv.z, mv.w};
#pragma unroll
      for (int i = 0; i < 8; i++)
#pragma unroll
        for (int j = 0; j < 4; j++) acc[i][j] += xv[i] * mm4[j];
    }
    __syncthreads();
  }
#pragma unroll
  for (int i = 0; i < 8; i++)
    *(float4*)&dst[(size_t)(x0 + ty * 8 + i) * NC + c0 + tx * 4] =
        make_float4(acc[i][0], acc[i][1], acc[i][2], acc[i][3]);
}

// ---------------------------------------------------------------------------
// 7. R10: fused row-wise fp16 Markidis split + style ssq.
//    One wave per row y: float4 reads of [y][c], packed 8B h/l stores,
//    shuffle-reduced sum of squares (unscaled) for feat==style.
__global__ __launch_bounds__(256) void split_kernel(const float* __restrict__ ncwT,
                                                    const float* __restrict__ nswT,
                                                    _Float16* __restrict__ BhiT,
                                                    _Float16* __restrict__ BloT,
                                                    _Float16* __restrict__ AhiT,
                                                    _Float16* __restrict__ AloT,
                                                    float* __restrict__ ssq) {
  int z = blockIdx.z; int feat = z >> 2, b = z & 3;
  int wave = threadIdx.x >> 6, lane = threadIdx.x & 63;
  int y = blockIdx.x * 4 + wave;
  const float* src = (feat ? nswT : ncwT) + ((size_t)b * NP + y) * NC;
  _Float16* oh = (feat ? AhiT : BhiT) + ((size_t)b * NP + y) * NC;
  _Float16* ol = (feat ? AloT : BloT) + ((size_t)b * NP + y) * NC;
  float4 v = *(const float4*)&src[lane * 4];
  float vv[4] = {v.x, v.y, v.z, v.w};
  h4v h, l;
#pragma unroll
  for (int q = 0; q < 4; q++) {
    float sv = vv[q] * SPLIT_SCALE;
    _Float16 hh = (_Float16)sv;          // v_cvt_f16_f32, RTN
    h[q] = hh;
    l[q] = (_Float16)(sv - (float)hh);
  }
  *(h4v*)&oh[lane * 4] = h;
  *(h4v*)&ol[lane * 4] = l;
  if (feat) {
    float s = vv[0] * vv[0] + vv[1] * vv[1] + vv[2] * vv[2] + vv[3] * vv[3];
#pragma unroll
    for (int off = 32; off > 0; off >>= 1) s += __shfl_down(s, off);
    if (lane == 0) ssq[b * NP + y] = s;
  }
}

__global__ __launch_bounds__(256) void rknorm_kernel(const float* __restrict__ ssq,
                                                     float* __restrict__ rk) {
  int idx = blockIdx.x * 256 + threadIdx.x;
  int b = idx >> 12, p = idx & 4095;
  int pi = p >> 6, pj = p & 63;
  float s = 0.f;
#pragma unroll
  for (int d = -1; d <= 1; d++)
#pragma unroll
    for (int e = -1; e <= 1; e++) {
      if ((unsigned)(pi + d) < 64u && (unsigned)(pj + e) < 64u)
        s += ssq[b * NP + (pi + d) * 64 + pj + e];
    }
  rk[idx] = 1.0f / sqrtf(s);
}

// ---------------------------------------------------------------------------
// 8. MFMA: D[p][x] = sum_c A[p][c]*B[x][c] via 3-term fp16 split (hh, hl, lh).
//    128x128 tile/block, 4 waves each 64x64 (4x4 of mfma_f32_16x16x32_f16),
//    BK=32, global_load_lds 16B staging.
__global__ __launch_bounds__(256) void dmat_kernel(const _Float16* __restrict__ AhiT,
                                                   const _Float16* __restrict__ AloT,
                                                   const _Float16* __restrict__ BhiT,
                                                   const _Float16* __restrict__ BloT,
                                                   float* __restrict__ D, int b) {
  __shared__ _Float16 sAh[128 * 32], sAl[128 * 32], sBh[128 * 32], sBl[128 * 32];
  const _Float16* Ah = AhiT + (size_t)b * NP * NC;
  const _Float16* Al = AloT + (size_t)b * NP * NC;
  const _Float16* Bh = BhiT + (size_t)b * NP * NC;
  const _Float16* Bl = BloT + (size_t)b * NP * NC;
  int p0 = blockIdx.x * 128, x0 = blockIdx.y * 128;
  int tid = threadIdx.x, lane = tid & 63;
  int m = lane & 15, quad = lane >> 4;
  int w = tid >> 6, qr = w & 1, qc = w >> 1;
  f4v acc[4][4] = {};
  for (int step = 0; step < NC / 32; step++) {
    int c0 = step * 32;
    __syncthreads();
#pragma unroll
    for (int i = 0; i < 2; i++) {
      int seg = i * 256 + tid;
      int row = seg >> 2, koff = (seg & 3) * 8;
      int sbase = (i * 256 + (tid & ~63)) * 8;   // wave-uniform
      GLD16(&sAh[sbase], Ah + (size_t)(p0 + row) * NC + c0 + koff);
      GLD16(&sAl[sbase], Al + (size_t)(p0 + row) * NC + c0 + koff);
      GLD16(&sBh[sbase], Bh + (size_t)(x0 + row) * NC + c0 + koff);
      GLD16(&sBl[sbase], Bl + (size_t)(x0 + row) * NC + c0 + koff);
    }
    __syncthreads();   // drains vmcnt (global_load_lds) per barrier semantics
    h8v afh[4], afl[4], bfh[4], bfl[4];
#pragma unroll
    for (int t = 0; t < 4; t++) {
      int ra = (qr * 64 + t * 16 + m) * 32 + quad * 8;
      afh[t] = *(const h8v*)&sAh[ra];
      afl[t] = *(const h8v*)&sAl[ra];
      int rb = (qc * 64 + t * 16 + m) * 32 + quad * 8;
      bfh[t] = *(const h8v*)&sBh[rb];
      bfl[t] = *(const h8v*)&sBl[rb];
    }
#pragma unroll
    for (int tr = 0; tr < 4; tr++)
#pragma unroll
      for (int tc = 0; tc < 4; tc++) {
        acc[tr][tc] = __builtin_amdgcn_mfma_f32_16x16x32_f16(afh[tr], bfh[tc], acc[tr][tc], 0, 0, 0);
        acc[tr][tc] = __builtin_amdgcn_mfma_f32_16x16x32_f16(afh[tr], bfl[tc], acc[tr][tc], 0, 0, 0);
        acc[tr][tc] = __builtin_amdgcn_mfma_f32_16x16x32_f16(afl[tr], bfh[tc], acc[tr][tc], 0, 0, 0);
      }
  }
  // C/D layout: col = lane&15, row = quad*4 + reg  [verified mapping]
#pragma unroll
  for (int tr = 0; tr < 4; tr++)
#pragma unroll
    for (int tc = 0; tc < 4; tc++)
#pragma unroll
      for (int r = 0; r < 4; r++) {
        int row = p0 + qr * 64 + tr * 16 + quad * 4 + r;
        int col = x0 + qc * 64 + tc * 16 + m;
        D[(size_t)row * NP + col] = acc[tr][tc][r];
      }
}

// ---------------------------------------------------------------------------
// 9. score[p][x] = (sum_{3x3 masked} D[p+off][x+off]) * rk[p]; partial argmax per p-slab
__global__ __launch_bounds__(256) void score_kernel(const float* __restrict__ D,
                                                    const float* __restrict__ rk,
                                                    float* __restrict__ pbest,
                                                    int* __restrict__ pidx, int b) {
  int x = blockIdx.x * 256 + threadIdx.x;
  int slab = blockIdx.y;
  int xi = x >> 6, xj = x & 63;
  const float* rkb = rk + (size_t)b * NP;
  bool xm[9];
#pragma unroll
  for (int q = 0; q < 9; q++) {
    int d = q / 3 - 1, e = q % 3 - 1;
    xm[q] = ((unsigned)(xi + d) < 64u) && ((unsigned)(xj + e) < 64u);
  }
  float best = -1e30f;
  int bi = 0;
  int p0 = slab * PSLAB;
  for (int p = p0; p < p0 + PSLAB; p++) {
    int pi = p >> 6, pj = p & 63;
    float acc = 0.f;
#pragma unroll
    for (int q = 0; q < 9; q++) {
      int d = q / 3 - 1, e = q % 3 - 1;
      int off = d * 64 + e;
      bool ok = xm[q] && ((unsigned)(pi + d) < 64u) && ((unsigned)(pj + e) < 64u);
      int row = ok ? p + off : p;
      int col = ok ? x + off : x;
      float t = D[(size_t)row * NP + col];
      acc += ok ? t : 0.f;
    }
    float s = acc * rkb[p];
    if (s > best) { best = s; bi = p; }
  }
  pbest[slab * NP + x] = best;
  pidx[slab * NP + x] = bi;
}

__global__ __launch_bounds__(256) void combine_kernel(const float* __restrict__ pbest,
                                                      const int* __restrict__ pidx,
                                                      int* __restrict__ bidx, int b) {
  int x = blockIdx.x * 256 + threadIdx.x;
  float best = pbest[x];
  int bi = pidx[x];
  for (int s = 1; s < NSLAB; s++) {
    float v = pbest[s * NP + x];
    if (v > best) { best = v; bi = pidx[s * NP + x]; }
  }
  bidx[b * NP + x] = bi;
}

// ---------------------------------------------------------------------------
// 11. gather-form overlap-add reassembly, divided by deconv norm.
//     R10: consumes nswT ([p][c] from whiten) directly — transpose_kernel dead.
__global__ __launch_bounds__(256) void reassemble_kernel(const float* __restrict__ nswT,
                                                         const int* __restrict__ bidx,
                                                         float* __restrict__ reass) {
  int by = blockIdx.x;       // b*NP + y
  int b = by >> 12, y = by & 4095;
  int yi = y >> 6, yj = y & 63;
  int t = threadIdx.x;       // channel
  float acc = 0.f;
#pragma unroll
  for (int oi = 0; oi < 3; oi++)
#pragma unroll
    for (int oj = 0; oj < 3; oj++) {
      int xi = yi + 1 - oi, xj = yj + 1 - oj;
      if ((unsigned)xi < 64u && (unsigned)xj < 64u) {
        int p = bidx[b * NP + xi * 64 + xj];
        int qi = (p >> 6) + oi - 1, qj = (p & 63) + oj - 1;
        if ((unsigned)qi < 64u && (unsigned)qj < 64u)
          acc += nswT[((size_t)b * NP + qi * 64 + qj) * NC + t];
      }
    }
  int cy = (yi == 0 || yi == 63) ? 2 : 3;
  int cx = (yj == 0 || yj == 63) ? 2 : 3;
  reass[((size_t)b * NP + y) * NC + t] = acc / (float)(cy * cx);
}

// ---------------------------------------------------------------------------
// 12. coloring: out[b][c][y] = sum_j sqr_s[b][c][j]*reass[b][y][j] + mean_s[b][c].
//     sqr_s symmetric -> As staged from rows (float4, conflict-free).
__global__ __launch_bounds__(256) void coloring_kernel(const float* __restrict__ sqr_s,
                                                       const float* __restrict__ reass,
                                                       const float* __restrict__ mean,
                                                       float* __restrict__ out) {
  int b = blockIdx.z;
  const float* A = sqr_s + (size_t)b * NC * NC;
  const float* Bm = reass + (size_t)b * NP * NC;
  const float* mu = mean + (size_t)NB * NC + b * NC;
  float* dst = out + (size_t)b * NC * NP;
  int c0 = blockIdx.x * 64, y0 = blockIdx.y * 64;
  __shared__ float As[32][68];   // [j][c], float4 rows
  __shared__ float Bs[32][66];   // [j][y], transposed scalar writes
  int tid = threadIdx.x, tx = tid & 15, ty = tid >> 4;
  float acc[4][4] = {};
  for (int k0 = 0; k0 < NC; k0 += 32) {
    for (int idx = tid; idx < 512; idx += 256) {
      int kk = idx >> 4, r4 = (idx & 15) * 4;   // A symmetric: row k, cols c
      *(float4*)&As[kk][r4] = *(const float4*)&A[(size_t)(k0 + kk) * NC + c0 + r4];
    }
    for (int idx = tid; idx < 2048; idx += 256) {
      int r = idx >> 5, kk = idx & 31;
      Bs[kk][r] = Bm[(size_t)(y0 + r) * NC + k0 + kk];
    }
    __syncthreads();
#pragma unroll
    for (int kk = 0; kk < 32; kk++) {
      float4 av = *(const float4*)&As[kk][ty * 4];
      float a[4] = {av.x, av.y, av.z, av.w};
      float bb[4];
      *(float2*)&bb[0] = *(const float2*)&Bs[kk][tx * 4];
      *(float2*)&bb[2] = *(const float2*)&Bs[kk][tx * 4 + 2];
#pragma unroll
      for (int i = 0; i < 4; i++)
#pragma unroll
        for (int j = 0; j < 4; j++) acc[i][j] += a[i] * bb[j];
    }
    __syncthreads();
  }
#pragma unroll
  for (int i = 0; i < 4; i++) {
    float m = mu[c0 + ty * 4 + i];
    float4 v = make_float4(acc[i][0] + m, acc[i][1] + m, acc[i][2] + m, acc[i][3] + m);
    *(float4*)&dst[(size_t)(c0 + ty * 4 + i) * NP + y0 + tx * 4] = v;
  }
}

// ---------------------------------------------------------------------------
extern "C" void kernel_launch(void* const* d_in, const int* in_sizes, int n_in,
                              void* d_out, int out_size, void* d_ws, size_t ws_size,
                              hipStream_t stream) {
  (void)in_sizes; (void)n_in; (void)out_size; (void)ws_size;
  const float* content = (const float*)d_in[0];
  const float* style = (const float*)d_in[1];
  float* out = (float*)d_out;

  // workspace carve-up (256B aligned)
  char* w = (char*)d_ws;
  auto alloc = [&](size_t bytes) -> void* {
    void* p = (void*)w;
    w += (bytes + 255) & ~(size_t)255;
    return p;
  };
  float* mean = (float*)alloc(2 * NB * NC * sizeof(float));
  double* pcov = (double*)alloc((size_t)KSPLIT * NM * NC * NC * sizeof(double));  // 32MB
  double* cov = (double*)alloc((size_t)NM * NC * NC * sizeof(double));
  double* Y0 = (double*)alloc((size_t)NM * NC * NC * sizeof(double));
  double* Z0 = (double*)alloc((size_t)NM * NC * NC * sizeof(double));
  double* Y1 = (double*)alloc((size_t)NM * NC * NC * sizeof(double));
  double* Z1 = (double*)alloc((size_t)NM * NC * NC * sizeof(double));
  double* T = (double*)alloc((size_t)NM * NC * NC * sizeof(double));
  double* scaleArr = (double*)alloc(NM * sizeof(double));
  float* inv_c = (float*)alloc((size_t)NB * NC * NC * sizeof(float));
  float* inv_s = (float*)alloc((size_t)NB * NC * NC * sizeof(float));
  float* sqr_s = (float*)alloc((size_t)NB * NC * NC * sizeof(float));
  float* ncwT = (float*)alloc((size_t)NB * NP * NC * sizeof(float));  // [p][c]
  float* nswT = (float*)alloc((size_t)NB * NP * NC * sizeof(float));  // [p][c]
  float* ssq = (float*)alloc((size_t)NB * NP * sizeof(float));
  float* rk = (float*)alloc((size_t)NB * NP * sizeof(float));
  float* pbest = (float*)alloc((size_t)NSLAB * NP * sizeof(float));
  int* pidx = (int*)alloc((size_t)NSLAB * NP * sizeof(int));
  int* bidx = (int*)alloc((size_t)NB * NP * sizeof(int));
  float* Dbuf = (float*)alloc((size_t)NP * NP * sizeof(float));  // 64MB, reused after score:
  float* reass = Dbuf + (size_t)NB * NP * NC;          // [16MB, 32MB) (D dead by then)
  // fp16 split arrays overlay pcov (dead after cov_reduce): 4 x 8MB = 32MB exactly
  _Float16* AhiT = (_Float16*)pcov;
  _Float16* AloT = AhiT + (size_t)NB * NP * NC;
  _Float16* BhiT = AloT + (size_t)NB * NP * NC;
  _Float16* BloT = BhiT + (size_t)NB * NP * NC;

  // 1-2: stats
  mean_kernel<<<2 * NB * NC, 256, 0, stream>>>(content, style, mean);
  cov_kernel<<<dim3(10, KSPLIT, NM), 256, 0, stream>>>(content, style, mean, pcov);
  cov_reduce_kernel<<<NM * NC * NC / 256, 256, 0, stream>>>(pcov, cov);

  // 3-4: Newton-Schulz inverse/forward sqrt in fp64 (Gershgorin-scaled)
  bound_init_kernel<<<NM, 256, 0, stream>>>(cov, Y0, Z0, scaleArr);
  double *Ya = Y0, *Za = Z0, *Yb = Y1, *Zb = Z1;
  for (int it = 0; it < NS_ITERS; it++) {
    ns_t_kernel<<<dim3(8, 8, NM), 256, 0, stream>>>(Za, Ya, T);
    ns_upd_kernel<<<dim3(8, 8, NM * 2), 256, 0, stream>>>(Ya, Za, T, Yb, Zb);
    double* tmp;
    tmp = Ya; Ya = Yb; Yb = tmp;
    tmp = Za; Za = Zb; Zb = tmp;
  }
  finalize_kernel<<<dim3(NB * NC * NC / 256, 3), 256, 0, stream>>>(Ya, Za, scaleArr,
                                                                   inv_c, inv_s, sqr_s);

  // 6: whiten both features, output [p][c] directly
  whiten_kernel<<<dim3(NP / 128, NC / 64, 2 * NB), 256, 0, stream>>>(
      content, style, mean, inv_c, inv_s, ncwT, nswT);

  // 7: fused fp16 split + style ssq (row-wise), then knorm box
  split_kernel<<<dim3(NP / 4, 1, 2 * NB), 256, 0, stream>>>(ncwT, nswT,
                                                            BhiT, BloT, AhiT, AloT, ssq);
  rknorm_kernel<<<NB * NP / 256, 256, 0, stream>>>(ssq, rk);

  // 8-9: per batch: D = A B^T (MFMA fp16 3-term), then shifted-sum score + argmax
  for (int b = 0; b < NB; b++) {
    dmat_kernel<<<dim3(NP / 128, NP / 128), 256, 0, stream>>>(AhiT, AloT, BhiT, BloT, Dbuf, b);
    score_kernel<<<dim3(NP / 256, NSLAB), 256, 0, stream>>>(Dbuf, rk, pbest, pidx, b);
    combine_kernel<<<NP / 256, 256, 0, stream>>>(pbest, pidx, bidx, b);
  }

  // 11: reassembly (gather form) straight from nswT
  reassemble_kernel<<<NB * NP, 256, 0, stream>>>(nswT, bidx, reass);

  // 12: coloring straight into d_out (style_strength == 1.0)
  coloring_kernel<<<dim3(NC / 64, NP / 64, NB), 256, 0, stream>>>(sqr_s, reass, mean, out);
}

// Round 11
// 1257.880 us; speedup vs baseline: 1.0341x; 1.0077x over previous
//
#include <hip/hip_runtime.h>
#include <stdint.h>

// Problem constants
constexpr int NB = 4;      // batch
constexpr int NC = 256;    // channels
constexpr int HW = 64;     // spatial side
constexpr int NP = 4096;   // HW*HW
constexpr int NM = 8;      // matrices for Newton-Schulz: 2 feats x 4 batches
constexpr int NS_ITERS = 7;       // lam_scaled ~0.135 -> residual 4.4e-13 at 7 (fp32 floor 6e-8)
constexpr int NSLAB = 64;         // R2: score occupancy fix
constexpr int PSLAB = NP / NSLAB; // 64
constexpr int KSPLIT = 8;         // cov K-split
constexpr int KCHUNK = NP / KSPLIT; // 512

// fp16 Markidis split (bf16 2-split caused argmax flips). Pre-scale by 512
// keeps lo out of fp16-subnormal range; uniform scaling is argmax-invariant
// for D, and is divided back out for cov.
constexpr float SPLIT_SCALE = 512.0f;
constexpr double COV_DESCALE = 1.0 / ((double)SPLIT_SCALE * (double)SPLIT_SCALE);

typedef __attribute__((ext_vector_type(8))) _Float16 h8v;  // 8 fp16 (4 VGPRs)
typedef __attribute__((ext_vector_type(4))) _Float16 h4v;  // 4 fp16 (8B store)
typedef __attribute__((ext_vector_type(4))) float f4v;     // MFMA acc

// async global->LDS, 16B per lane; lds arg must be wave-uniform
#define GLD16(lds, g)                                                        \
  __builtin_amdgcn_global_load_lds(                                          \
      (const __attribute__((address_space(1))) void*)(g),                    \
      (__attribute__((address_space(3))) void*)(lds), 16, 0, 0)

// ---------------------------------------------------------------------------
// 1. R11: fused mean + raw fp16 split. Phase 1: row mean (BIT-IDENTICAL
//    reduction order to the old mean_kernel -> whiten unchanged). Phase 2:
//    re-read row (L1/L2-hot) and emit (src-mu)*512 as fp16 hi/lo in [c][p]
//    (p-contiguous — cov contracts over p, so NO transpose is ever needed).
__global__ __launch_bounds__(256) void meansplit_kernel(const float* __restrict__ content,
                                                        const float* __restrict__ style,
                                                        float* __restrict__ mean,
                                                        _Float16* __restrict__ Czh,
                                                        _Float16* __restrict__ Czl) {
  int id = blockIdx.x;              // [0, 2*NB*NC) == m*NC + c
  int feat = id / (NB * NC);
  int bc = id % (NB * NC);
  const float* src = (feat ? style : content) + (size_t)bc * NP;
  int tid = threadIdx.x;
  float s = 0.f;
  for (int i = tid; i < NP; i += 256) s += src[i];
  __shared__ float red[256];
  red[tid] = s;
  __syncthreads();
  for (int st = 128; st > 0; st >>= 1) {
    if (tid < st) red[tid] += red[tid + st];
    __syncthreads();
  }
  float mu = red[0] * (1.0f / NP);
  if (tid == 0) mean[id] = mu;
  _Float16* oh = Czh + (size_t)id * NP;
  _Float16* ol = Czl + (size_t)id * NP;
  for (int f4 = tid; f4 < NP / 4; f4 += 256) {
    float4 v = *(const float4*)&src[f4 * 4];
    float vv[4] = {v.x, v.y, v.z, v.w};
    h4v h, l;
#pragma unroll
    for (int q = 0; q < 4; q++) {
      float sv = (vv[q] - mu) * SPLIT_SCALE;
      _Float16 hh = (_Float16)sv;
      h[q] = hh;
      l[q] = (_Float16)(sv - (float)hh);
    }
    *(h4v*)&oh[f4 * 4] = h;
    *(h4v*)&ol[f4 * 4] = l;
  }
}

// ---------------------------------------------------------------------------
// 2. R11: MFMA syrk cov. pcov[ks][m] += Z[i0..][k] * Z[j0..][k] over K-chunk,
//    64x64 upper-tri tiles, 4-term fp16 split (hh+hl+lh+ll: representation
//    error ~2^-33), per-32-k fp64 fold of fp32 MFMA acc -> cov rel err ~1e-7
//    (better than the old fp32-product path). dmat-verified lane mappings.
__global__ __launch_bounds__(256) void cov_mfma_kernel(const _Float16* __restrict__ Czh,
                                                       const _Float16* __restrict__ Czl,
                                                       double* __restrict__ pcov) {
  __shared__ _Float16 sAh[64 * 32], sAl[64 * 32], sBh[64 * 32], sBl[64 * 32];
  int m = blockIdx.z;
  int t = blockIdx.x, ti = 0, rem = t;
  while (rem >= 4 - ti) { rem -= 4 - ti; ti++; }
  int tj = ti + rem;
  int i0 = ti * 64, j0 = tj * 64;
  const _Float16* Ah = Czh + ((size_t)m * NC + i0) * NP;
  const _Float16* Al = Czl + ((size_t)m * NC + i0) * NP;
  const _Float16* Bh = Czh + ((size_t)m * NC + j0) * NP;
  const _Float16* Bl = Czl + ((size_t)m * NC + j0) * NP;
  int k0base = blockIdx.y * KCHUNK;
  int tid = threadIdx.x, lane = tid & 63;
  int mm = lane & 15, quad = lane >> 4;
  int w = tid >> 6, qr = w & 1, qc = w >> 1;
  double dacc[2][2][4] = {};
  for (int step = 0; step < KCHUNK / 32; step++) {
    int k0 = k0base + step * 32;
    __syncthreads();
    {
      int row = tid >> 2, koff = (tid & 3) * 8;
      int sbase = (tid & ~63) * 8;   // wave-uniform; lane l lands at sbase+l*8 (verified)
      GLD16(&sAh[sbase], Ah + (size_t)row * NP + k0 + koff);
      GLD16(&sAl[sbase], Al + (size_t)row * NP + k0 + koff);
      GLD16(&sBh[sbase], Bh + (size_t)row * NP + k0 + koff);
      GLD16(&sBl[sbase], Bl + (size_t)row * NP + k0 + koff);
    }
    __syncthreads();   // drains vmcnt per barrier semantics
    h8v afh[2], afl[2], bfh[2], bfl[2];
#pragma unroll
    for (int tt = 0; tt < 2; tt++) {
      int ra = (qr * 32 + tt * 16 + mm) * 32 + quad * 8;
      afh[tt] = *(const h8v*)&sAh[ra];
      afl[tt] = *(const h8v*)&sAl[ra];
      int rb = (qc * 32 + tt * 16 + mm) * 32 + quad * 8;
      bfh[tt] = *(const h8v*)&sBh[rb];
      bfl[tt] = *(const h8v*)&sBl[rb];
    }
    f4v acc[2][2] = {};
#pragma unroll
    for (int tr = 0; tr < 2; tr++)
#pragma unroll
      for (int tc = 0; tc < 2; tc++) {
        acc[tr][tc] = __builtin_amdgcn_mfma_f32_16x16x32_f16(afh[tr], bfh[tc], acc[tr][tc], 0, 0, 0);
        acc[tr][tc] = __builtin_amdgcn_mfma_f32_16x16x32_f16(afh[tr], bfl[tc], acc[tr][tc], 0, 0, 0);
        acc[tr][tc] = __builtin_amdgcn_mfma_f32_16x16x32_f16(afl[tr], bfh[tc], acc[tr][tc], 0, 0, 0);
        acc[tr][tc] = __builtin_amdgcn_mfma_f32_16x16x32_f16(afl[tr], bfl[tc], acc[tr][tc], 0, 0, 0);
      }
#pragma unroll
    for (int tr = 0; tr < 2; tr++)
#pragma unroll
      for (int tc = 0; tc < 2; tc++)
#pragma unroll
        for (int r = 0; r < 4; r++) dacc[tr][tc][r] += (double)acc[tr][tc][r];
  }
  double* dst = pcov + ((size_t)blockIdx.y * NM + m) * NC * NC;
  // C/D layout: col = lane&15, row = quad*4 + reg  [verified mapping]
#pragma unroll
  for (int tr = 0; tr < 2; tr++)
#pragma unroll
    for (int tc = 0; tc < 2; tc++)
#pragma unroll
      for (int r = 0; r < 4; r++) {
        int row = i0 + qr * 32 + tr * 16 + quad * 4 + r;
        int col = j0 + qc * 32 + tc * 16 + mm;
        dst[(size_t)row * NC + col] = dacc[tr][tc][r];
      }
}

// 2b. sum K-split partials; mirror lower triangle from upper tiles; descale
__global__ __launch_bounds__(256) void cov_reduce_kernel(const double* __restrict__ pcov,
                                                         double* __restrict__ cov) {
  size_t idx = (size_t)blockIdx.x * 256 + threadIdx.x;  // [0, NM*NC*NC)
  int m = (int)(idx >> 16);
  int ij = (int)(idx & 65535);
  int i = ij >> 8, j = ij & 255;
  int src = ((i >> 6) <= (j >> 6)) ? ij : ((j << 8) | i);
  double s = 0;
  for (int k = 0; k < KSPLIT; k++)
    s += pcov[((size_t)k * NM + m) * 65536 + src];
  cov[idx] = s * COV_DESCALE;
}

// ---------------------------------------------------------------------------
// 3. Gershgorin bound (abs row sum, A symmetric); init Y = s*A, Z = I
__global__ __launch_bounds__(256) void bound_init_kernel(const double* __restrict__ cov,
                                                         double* __restrict__ Y,
                                                         double* __restrict__ Z,
                                                         double* __restrict__ scaleArr) {
  int m = blockIdx.x;
  const double* A = cov + (size_t)m * NC * NC;
  int t = threadIdx.x;
  double s = 0;
  for (int i = 0; i < NC; i++) s += fabs(A[(size_t)i * NC + t]);   // coalesced
  __shared__ double red[256];
  red[t] = s;
  __syncthreads();
  for (int st = 128; st > 0; st >>= 1) {
    if (t < st) red[t] = fmax(red[t], red[t + st]);
    __syncthreads();
  }
  double scale = 1.0 / red[0];     // lam_max <= max abs row sum (rigorous upper bound)
  if (t == 0) scaleArr[m] = scale;
  double* Ym = Y + (size_t)m * NC * NC;
  double* Zm = Z + (size_t)m * NC * NC;
  for (int idx = t; idx < NC * NC; idx += 256) {
    Ym[idx] = A[idx] * scale;
    Zm[idx] = ((idx / NC) == (idx % NC)) ? 1.0 : 0.0;
  }
}

// ---------------------------------------------------------------------------
// 4a. T = Z * Y (fp64, 32x32 tiles, 2x2 micro)
__global__ __launch_bounds__(256) void ns_t_kernel(const double* __restrict__ Zin,
                                                   const double* __restrict__ Yin,
                                                   double* __restrict__ T) {
  int m = blockIdx.z;
  const double* Am = Zin + (size_t)m * NC * NC;
  const double* Bm = Yin + (size_t)m * NC * NC;
  double* Tm = T + (size_t)m * NC * NC;
  __shared__ double As[32][33];
  __shared__ double Bs[32][33];
  int tid = threadIdx.x, tx = tid & 15, ty = tid >> 4;
  int i0 = blockIdx.x * 32, j0 = blockIdx.y * 32;
  double a00 = 0, a01 = 0, a10 = 0, a11 = 0;
  for (int k0 = 0; k0 < NC; k0 += 32) {
    for (int idx = tid; idx < 1024; idx += 256) {
      int r = idx >> 5, cc = idx & 31;
      As[r][cc] = Am[(size_t)(i0 + r) * NC + k0 + cc];
      Bs[r][cc] = Bm[(size_t)(k0 + r) * NC + j0 + cc];
    }
    __syncthreads();
#pragma unroll
    for (int kk = 0; kk < 32; kk++) {
      double x0 = As[ty * 2][kk], x1 = As[ty * 2 + 1][kk];
      double y0 = Bs[kk][tx * 2], y1 = Bs[kk][tx * 2 + 1];
      a00 += x0 * y0; a01 += x0 * y1; a10 += x1 * y0; a11 += x1 * y1;
    }
    __syncthreads();
  }
  Tm[(size_t)(i0 + ty * 2) * NC + j0 + tx * 2] = a00;
  Tm[(size_t)(i0 + ty * 2) * NC + j0 + tx * 2 + 1] = a01;
  Tm[(size_t)(i0 + ty * 2 + 1) * NC + j0 + tx * 2] = a10;
  Tm[(size_t)(i0 + ty * 2 + 1) * NC + j0 + tx * 2 + 1] = a11;
}

// 4b. Yout = 1.5*Yin - 0.5*Yin*T ; Zout = 1.5*Zin - 0.5*T*Zin
__global__ __launch_bounds__(256) void ns_upd_kernel(const double* __restrict__ Yin,
                                                     const double* __restrict__ Zin,
                                                     const double* __restrict__ T,
                                                     double* __restrict__ Yout,
                                                     double* __restrict__ Zout) {
  int z = blockIdx.z;
  int m = z & 7, which = z >> 3;
  size_t off = (size_t)m * NC * NC;
  const double* Am = which == 0 ? (Yin + off) : (T + off);
  const double* Bm = which == 0 ? (T + off) : (Zin + off);
  const double* Sm = which == 0 ? (Yin + off) : (Zin + off);
  double* Om = which == 0 ? (Yout + off) : (Zout + off);
  __shared__ double As[32][33];
  __shared__ double Bs[32][33];
  int tid = threadIdx.x, tx = tid & 15, ty = tid >> 4;
  int i0 = blockIdx.x * 32, j0 = blockIdx.y * 32;
  double a00 = 0, a01 = 0, a10 = 0, a11 = 0;
  for (int k0 = 0; k0 < NC; k0 += 32) {
    for (int idx = tid; idx < 1024; idx += 256) {
      int r = idx >> 5, cc = idx & 31;
      As[r][cc] = Am[(size_t)(i0 + r) * NC + k0 + cc];
      Bs[r][cc] = Bm[(size_t)(k0 + r) * NC + j0 + cc];
    }
    __syncthreads();
#pragma unroll
    for (int kk = 0; kk < 32; kk++) {
      double x0 = As[ty * 2][kk], x1 = As[ty * 2 + 1][kk];
      double y0 = Bs[kk][tx * 2], y1 = Bs[kk][tx * 2 + 1];
      a00 += x0 * y0; a01 += x0 * y1; a10 += x1 * y0; a11 += x1 * y1;
    }
    __syncthreads();
  }
  int r0 = i0 + ty * 2, c0 = j0 + tx * 2;
  Om[(size_t)r0 * NC + c0] = 1.5 * Sm[(size_t)r0 * NC + c0] - 0.5 * a00;
  Om[(size_t)r0 * NC + c0 + 1] = 1.5 * Sm[(size_t)r0 * NC + c0 + 1] - 0.5 * a01;
  Om[(size_t)(r0 + 1) * NC + c0] = 1.5 * Sm[(size_t)(r0 + 1) * NC + c0] - 0.5 * a10;
  Om[(size_t)(r0 + 1) * NC + c0 + 1] = 1.5 * Sm[(size_t)(r0 + 1) * NC + c0 + 1] - 0.5 * a11;
}

// ---------------------------------------------------------------------------
// 5. finalize: inv_c = Z_c*sqrt(s), inv_s = Z_s*sqrt(s), sqr_s = Y_s/sqrt(s)  (fp32)
__global__ __launch_bounds__(256) void finalize_kernel(const double* __restrict__ Yf,
                                                       const double* __restrict__ Zf,
                                                       const double* __restrict__ scaleArr,
                                                       float* __restrict__ inv_c,
                                                       float* __restrict__ inv_s,
                                                       float* __restrict__ sqr_s) {
  int which = blockIdx.y;
  int idx = blockIdx.x * 256 + threadIdx.x;   // [0, NB*NC*NC)
  int b = idx >> 16;
  int ij = idx & 65535;
  if (which == 0) {
    double s = sqrt(scaleArr[b]);
    inv_c[idx] = (float)(Zf[(size_t)b * 65536 + ij] * s);
  } else if (which == 1) {
    double s = sqrt(scaleArr[4 + b]);
    inv_s[idx] = (float)(Zf[(size_t)(4 + b) * 65536 + ij] * s);
  } else {
    double s = sqrt(scaleArr[4 + b]);
    sqr_s[idx] = (float)(Yf[(size_t)(4 + b) * 65536 + ij] / s);
  }
}

// ---------------------------------------------------------------------------
// 6. whitening: outT[x][c] = sum_k (src[k][x]-mu[k]) * M[k][c]. Emits [p][c]
//    directly. M symmetric -> Ms[k][c] staged from M rows (float4, conflict-free).
__global__ __launch_bounds__(256) void whiten_kernel(const float* __restrict__ content,
                                                     const float* __restrict__ style,
                                                     const float* __restrict__ mean,
                                                     const float* __restrict__ inv_c,
                                                     const float* __restrict__ inv_s,
                                                     float* __restrict__ ncwT,
                                                     float* __restrict__ nswT) {
  int z = blockIdx.z; int feat = z >> 2, b = z & 3;
  const float* src = (feat ? style : content) + (size_t)b * NC * NP;
  const float* mu = mean + (size_t)feat * NB * NC + b * NC;
  const float* M = (feat ? inv_s : inv_c) + (size_t)b * NC * NC;
  float* dst = (feat ? nswT : ncwT) + (size_t)b * NP * NC;   // [p][c]
  int x0 = blockIdx.x * 128, c0 = blockIdx.y * 64;
  __shared__ float Ms[32][68];    // [k][c]
  __shared__ float Xs[32][136];   // [k][x]
  int tid = threadIdx.x, tx = tid & 15, ty = tid >> 4;
  float acc[8][4] = {};   // [x_i][c_j]
  for (int k0 = 0; k0 < NC; k0 += 32) {
    for (int idx = tid; idx < 512; idx += 256) {
      int kk = idx >> 4, r4 = (idx & 15) * 4;
      *(float4*)&Ms[kk][r4] = *(const float4*)&M[(size_t)(k0 + kk) * NC + c0 + r4];
    }
    for (int idx = tid; idx < 1024; idx += 256) {
      int r = idx >> 5, c4 = (idx & 31) * 4;
      float4 v = *(const float4*)&src[(size_t)(k0 + r) * NP + x0 + c4];
      float mm = mu[k0 + r];
      v.x -= mm; v.y -= mm; v.z -= mm; v.w -= mm;
      *(float4*)&Xs[r][c4] = v;
    }
    __syncthreads();
#pragma unroll
    for (int kk = 0; kk < 32; kk++) {
      float4 xa = *(const float4*)&Xs[kk][ty * 8];
      float4 xb = *(const float4*)&Xs[kk][ty * 8 + 4];
      float4 mv = *(const float4*)&Ms[kk][tx * 4];
      float xv[8] = {xa.x, xa.y, xa.z, xa.w, xb.x, xb.y, xb.z, xb.w};
      float mm4[4] = {mv.x, mv.y, mv.z, mv.w};
#pragma unroll
      for (int i = 0; i < 8; i++)
#pragma unroll
        for (int j = 0; j < 4; j++) acc[i][j] += xv[i] * mm4[j];
    }
    __syncthreads();
  }
#pragma unroll
  for (int i = 0; i < 8; i++)
    *(float4*)&dst[(size_t)(x0 + ty * 8 + i) * NC + c0 + tx * 4] =
        make_float4(acc[i][0], acc[i][1], acc[i][2], acc[i][3]);
}

// ---------------------------------------------------------------------------
// 7. fused row-wise fp16 Markidis split + style ssq (one wave per row y)
__global__ __launch_bounds__(256) void split_kernel(const float* __restrict__ ncwT,
                                                    const float* __restrict__ nswT,
                                                    _Float16* __restrict__ BhiT,
                                                    _Float16* __restrict__ BloT,
                                                    _Float16* __restrict__ AhiT,
                                                    _Float16* __restrict__ AloT,
                                                    float* __restrict__ ssq) {
  int z = blockIdx.z; int feat = z >> 2, b = z & 3;
  int wave = threadIdx.x >> 6, lane = threadIdx.x & 63;
  int y = blockIdx.x * 4 + wave;
  const float* src = (feat ? nswT : ncwT) + ((size_t)b * NP + y) * NC;
  _Float16* oh = (feat ? AhiT : BhiT) + ((size_t)b * NP + y) * NC;
  _Float16* ol = (feat ? AloT : BloT) + ((size_t)b * NP + y) * NC;
  float4 v = *(const float4*)&src[lane * 4];
  float vv[4] = {v.x, v.y, v.z, v.w};
  h4v h, l;
#pragma unroll
  for (int q = 0; q < 4; q++) {
    float sv = vv[q] * SPLIT_SCALE;
    _Float16 hh = (_Float16)sv;          // v_cvt_f16_f32, RTN
    h[q] = hh;
    l[q] = (_Float16)(sv - (float)hh);
  }
  *(h4v*)&oh[lane * 4] = h;
  *(h4v*)&ol[lane * 4] = l;
  if (feat) {
    float s = vv[0] * vv[0] + vv[1] * vv[1] + vv[2] * vv[2] + vv[3] * vv[3];
#pragma unroll
    for (int off = 32; off > 0; off >>= 1) s += __shfl_down(s, off);
    if (lane == 0) ssq[b * NP + y] = s;
  }
}

__global__ __launch_bounds__(256) void rknorm_kernel(const float* __restrict__ ssq,
                                                     float* __restrict__ rk) {
  int idx = blockIdx.x * 256 + threadIdx.x;
  int b = idx >> 12, p = idx & 4095;
  int pi = p >> 6, pj = p & 63;
  float s = 0.f;
#pragma unroll
  for (int d = -1; d <= 1; d++)
#pragma unroll
    for (int e = -1; e <= 1; e++) {
      if ((unsigned)(pi + d) < 64u && (unsigned)(pj + e) < 64u)
        s += ssq[b * NP + (pi + d) * 64 + pj + e];
    }
  rk[idx] = 1.0f / sqrtf(s);
}

// ---------------------------------------------------------------------------
// 8. MFMA: D[p][x] = sum_c A[p][c]*B[x][c] via 3-term fp16 split (hh, hl, lh).
//    128x128 tile/block, 4 waves each 64x64 (4x4 of mfma_f32_16x16x32_f16),
//    BK=32, global_load_lds 16B staging.
__global__ __launch_bounds__(256) void dmat_kernel(const _Float16* __restrict__ AhiT,
                                                   const _Float16* __restrict__ AloT,
                                                   const _Float16* __restrict__ BhiT,
                                                   const _Float16* __restrict__ BloT,
                                                   float* __restrict__ D, int b) {
  __shared__ _Float16 sAh[128 * 32], sAl[128 * 32], sBh[128 * 32], sBl[128 * 32];
  const _Float16* Ah = AhiT + (size_t)b * NP * NC;
  const _Float16* Al = AloT + (size_t)b * NP * NC;
  const _Float16* Bh = BhiT + (size_t)b * NP * NC;
  const _Float16* Bl = BloT + (size_t)b * NP * NC;
  int p0 = blockIdx.x * 128, x0 = blockIdx.y * 128;
  int tid = threadIdx.x, lane = tid & 63;
  int m = lane & 15, quad = lane >> 4;
  int w = tid >> 6, qr = w & 1, qc = w >> 1;
  f4v acc[4][4] = {};
  for (int step = 0; step < NC / 32; step++) {
    int c0 = step * 32;
    __syncthreads();
#pragma unroll
    for (int i = 0; i < 2; i++) {
      int seg = i * 256 + tid;
      int row = seg >> 2, koff = (seg & 3) * 8;
      int sbase = (i * 256 + (tid & ~63)) * 8;   // wave-uniform
      GLD16(&sAh[sbase], Ah + (size_t)(p0 + row) * NC + c0 + koff);
      GLD16(&sAl[sbase], Al + (size_t)(p0 + row) * NC + c0 + koff);
      GLD16(&sBh[sbase], Bh + (size_t)(x0 + row) * NC + c0 + koff);
      GLD16(&sBl[sbase], Bl + (size_t)(x0 + row) * NC + c0 + koff);
    }
    __syncthreads();   // drains vmcnt (global_load_lds) per barrier semantics
    h8v afh[4], afl[4], bfh[4], bfl[4];
#pragma unroll
    for (int t = 0; t < 4; t++) {
      int ra = (qr * 64 + t * 16 + m) * 32 + quad * 8;
      afh[t] = *(const h8v*)&sAh[ra];
      afl[t] = *(const h8v*)&sAl[ra];
      int rb = (qc * 64 + t * 16 + m) * 32 + quad * 8;
      bfh[t] = *(const h8v*)&sBh[rb];
      bfl[t] = *(const h8v*)&sBl[rb];
    }
#pragma unroll
    for (int tr = 0; tr < 4; tr++)
#pragma unroll
      for (int tc = 0; tc < 4; tc++) {
        acc[tr][tc] = __builtin_amdgcn_mfma_f32_16x16x32_f16(afh[tr], bfh[tc], acc[tr][tc], 0, 0, 0);
        acc[tr][tc] = __builtin_amdgcn_mfma_f32_16x16x32_f16(afh[tr], bfl[tc], acc[tr][tc], 0, 0, 0);
        acc[tr][tc] = __builtin_amdgcn_mfma_f32_16x16x32_f16(afl[tr], bfh[tc], acc[tr][tc], 0, 0, 0);
      }
  }
  // C/D layout: col = lane&15, row = quad*4 + reg  [verified mapping]
#pragma unroll
  for (int tr = 0; tr < 4; tr++)
#pragma unroll
    for (int tc = 0; tc < 4; tc++)
#pragma unroll
      for (int r = 0; r < 4; r++) {
        int row = p0 + qr * 64 + tr * 16 + quad * 4 + r;
        int col = x0 + qc * 64 + tc * 16 + m;
        D[(size_t)row * NP + col] = acc[tr][tc][r];
      }
}

// ---------------------------------------------------------------------------
// 9. score[p][x] = (sum_{3x3 masked} D[p+off][x+off]) * rk[p]; partial argmax per p-slab
__global__ __launch_bounds__(256) void score_kernel(const float* __restrict__ D,
                                                    const float* __restrict__ rk,
                                                    float* __restrict__ pbest,
                                                    int* __restrict__ pidx, int b) {
  int x = blockIdx.x * 256 + threadIdx.x;
  int slab = blockIdx.y;
  int xi = x >> 6, xj = x & 63;
  const float* rkb = rk + (size_t)b * NP;
  bool xm[9];
#pragma unroll
  for (int q = 0; q < 9; q++) {
    int d = q / 3 - 1, e = q % 3 - 1;
    xm[q] = ((unsigned)(xi + d) < 64u) && ((unsigned)(xj + e) < 64u);
  }
  float best = -1e30f;
  int bi = 0;
  int p0 = slab * PSLAB;
  for (int p = p0; p < p0 + PSLAB; p++) {
    int pi = p >> 6, pj = p & 63;
    float acc = 0.f;
#pragma unroll
    for (int q = 0; q < 9; q++) {
      int d = q / 3 - 1, e = q % 3 - 1;
      int off = d * 64 + e;
      bool ok = xm[q] && ((unsigned)(pi + d) < 64u) && ((unsigned)(pj + e) < 64u);
      int row = ok ? p + off : p;
      int col = ok ? x + off : x;
      float t = D[(size_t)row * NP + col];
      acc += ok ? t : 0.f;
    }
    float s = acc * rkb[p];
    if (s > best) { best = s; bi = p; }
  }
  pbest[slab * NP + x] = best;
  pidx[slab * NP + x] = bi;
}

__global__ __launch_bounds__(256) void combine_kernel(const float* __restrict__ pbest,
                                                      const int* __restrict__ pidx,
                                                      int* __restrict__ bidx, int b) {
  int x = blockIdx.x * 256 + threadIdx.x;
  float best = pbest[x];
  int bi = pidx[x];
  for (int s = 1; s < NSLAB; s++) {
    float v = pbest[s * NP + x];
    if (v > best) { best = v; bi = pidx[s * NP + x]; }
  }
  bidx[b * NP + x] = bi;
}

// ---------------------------------------------------------------------------
// 11. gather-form overlap-add reassembly, divided by deconv norm (reads nswT [p][c])
__global__ __launch_bounds__(256) void reassemble_kernel(const float* __restrict__ nswT,
                                                         const int* __restrict__ bidx,
                                                         float* __restrict__ reass) {
  int by = blockIdx.x;       // b*NP + y
  int b = by >> 12, y = by & 4095;
  int yi = y >> 6, yj = y & 63;
  int t = threadIdx.x;       // channel
  float acc = 0.f;
#pragma unroll
  for (int oi = 0; oi < 3; oi++)
#pragma unroll
    for (int oj = 0; oj < 3; oj++) {
      int xi = yi + 1 - oi, xj = yj + 1 - oj;
      if ((unsigned)xi < 64u && (unsigned)xj < 64u) {
        int p = bidx[b * NP + xi * 64 + xj];
        int qi = (p >> 6) + oi - 1, qj = (p & 63) + oj - 1;
        if ((unsigned)qi < 64u && (unsigned)qj < 64u)
          acc += nswT[((size_t)b * NP + qi * 64 + qj) * NC + t];
      }
    }
  int cy = (yi == 0 || yi == 63) ? 2 : 3;
  int cx = (yj == 0 || yj == 63) ? 2 : 3;
  reass[((size_t)b * NP + y) * NC + t] = acc / (float)(cy * cx);
}

// ---------------------------------------------------------------------------
// 12. coloring: out[b][c][y] = sum_j sqr_s[b][c][j]*reass[b][y][j] + mean_s[b][c].
//     sqr_s symmetric -> As staged from rows (float4, conflict-free).
__global__ __launch_bounds__(256) void coloring_kernel(const float* __restrict__ sqr_s,
                                                       const float* __restrict__ reass,
                                                       const float* __restrict__ mean,
                                                       float* __restrict__ out) {
  int b = blockIdx.z;
  const float* A = sqr_s + (size_t)b * NC * NC;
  const float* Bm = reass + (size_t)b * NP * NC;
  const float* mu = mean + (size_t)NB * NC + b * NC;
  float* dst = out + (size_t)b * NC * NP;
  int c0 = blockIdx.x * 64, y0 = blockIdx.y * 64;
  __shared__ float As[32][68];   // [j][c], float4 rows
  __shared__ float Bs[32][66];   // [j][y], transposed scalar writes
  int tid = threadIdx.x, tx = tid & 15, ty = tid >> 4;
  float acc[4][4] = {};
  for (int k0 = 0; k0 < NC; k0 += 32) {
    for (int idx = tid; idx < 512; idx += 256) {
      int kk = idx >> 4, r4 = (idx & 15) * 4;   // A symmetric: row k, cols c
      *(float4*)&As[kk][r4] = *(const float4*)&A[(size_t)(k0 + kk) * NC + c0 + r4];
    }
    for (int idx = tid; idx < 2048; idx += 256) {
      int r = idx >> 5, kk = idx & 31;
      Bs[kk][r] = Bm[(size_t)(y0 + r) * NC + k0 + kk];
    }
    __syncthreads();
#pragma unroll
    for (int kk = 0; kk < 32; kk++) {
      float4 av = *(const float4*)&As[kk][ty * 4];
      float a[4] = {av.x, av.y, av.z, av.w};
      float bb[4];
      *(float2*)&bb[0] = *(const float2*)&Bs[kk][tx * 4];
      *(float2*)&bb[2] = *(const float2*)&Bs[kk][tx * 4 + 2];
#pragma unroll
      for (int i = 0; i < 4; i++)
#pragma unroll
        for (int j = 0; j < 4; j++) acc[i][j] += a[i] * bb[j];
    }
    __syncthreads();
  }
#pragma unroll
  for (int i = 0; i < 4; i++) {
    float m = mu[c0 + ty * 4 + i];
    float4 v = make_float4(acc[i][0] + m, acc[i][1] + m, acc[i][2] + m, acc[i][3] + m);
    *(float4*)&dst[(size_t)(c0 + ty * 4 + i) * NP + y0 + tx * 4] = v;
  }
}

// ---------------------------------------------------------------------------
extern "C" void kernel_launch(void* const* d_in, const int* in_sizes, int n_in,
                              void* d_out, int out_size, void* d_ws, size_t ws_size,
                              hipStream_t stream) {
  (void)in_sizes; (void)n_in; (void)out_size; (void)ws_size;
  const float* content = (const float*)d_in[0];
  const float* style = (const float*)d_in[1];
  float* out = (float*)d_out;

  // workspace carve-up (256B aligned)
  char* w = (char*)d_ws;
  auto alloc = [&](size_t bytes) -> void* {
    void* p = (void*)w;
    w += (bytes + 255) & ~(size_t)255;
    return p;
  };
  float* mean = (float*)alloc(2 * NB * NC * sizeof(float));
  double* pcov = (double*)alloc((size_t)KSPLIT * NM * NC * NC * sizeof(double));  // 32MB
  double* cov = (double*)alloc((size_t)NM * NC * NC * sizeof(double));
  double* Y0 = (double*)alloc((size_t)NM * NC * NC * sizeof(double));
  double* Z0 = (double*)alloc((size_t)NM * NC * NC * sizeof(double));
  double* Y1 = (double*)alloc((size_t)NM * NC * NC * sizeof(double));
  double* Z1 = (double*)alloc((size_t)NM * NC * NC * sizeof(double));
  double* T = (double*)alloc((size_t)NM * NC * NC * sizeof(double));
  double* scaleArr = (double*)alloc(NM * sizeof(double));
  float* inv_c = (float*)alloc((size_t)NB * NC * NC * sizeof(float));
  float* inv_s = (float*)alloc((size_t)NB * NC * NC * sizeof(float));
  float* sqr_s = (float*)alloc((size_t)NB * NC * NC * sizeof(float));
  float* ncwT = (float*)alloc((size_t)NB * NP * NC * sizeof(float));  // [p][c]
  float* nswT = (float*)alloc((size_t)NB * NP * NC * sizeof(float));  // [p][c]
  float* ssq = (float*)alloc((size_t)NB * NP * sizeof(float));
  float* rk = (float*)alloc((size_t)NB * NP * sizeof(float));
  float* pbest = (float*)alloc((size_t)NSLAB * NP * sizeof(float));
  int* pidx = (int*)alloc((size_t)NSLAB * NP * sizeof(int));
  int* bidx = (int*)alloc((size_t)NB * NP * sizeof(int));
  float* Dbuf = (float*)alloc((size_t)NP * NP * sizeof(float));  // 64MB, multi-overlaid:
  float* reass = Dbuf + (size_t)NB * NP * NC;          // [16MB, 32MB), used after score loop
  // R11: raw fp16 split overlays Dbuf[0,32MB) — dead before dmat first writes Dbuf
  _Float16* Czh = (_Float16*)Dbuf;                       // 16MB: NM*NC*NP fp16
  _Float16* Czl = Czh + (size_t)NM * NC * NP;            // 16MB
  // whitened fp16 split arrays overlay pcov (dead after cov_reduce): 4 x 8MB
  _Float16* AhiT = (_Float16*)pcov;
  _Float16* AloT = AhiT + (size_t)NB * NP * NC;
  _Float16* BhiT = AloT + (size_t)NB * NP * NC;
  _Float16* BloT = BhiT + (size_t)NB * NP * NC;

  // 1-2: fused mean + raw split, then MFMA syrk cov (conflict-free, no transpose)
  meansplit_kernel<<<2 * NB * NC, 256, 0, stream>>>(content, style, mean, Czh, Czl);
  cov_mfma_kernel<<<dim3(10, KSPLIT, NM), 256, 0, stream>>>(Czh, Czl, pcov);
  cov_reduce_kernel<<<NM * NC * NC / 256, 256, 0, stream>>>(pcov, cov);

  // 3-4: Newton-Schulz inverse/forward sqrt in fp64 (Gershgorin-scaled)
  bound_init_kernel<<<NM, 256, 0, stream>>>(cov, Y0, Z0, scaleArr);
  double *Ya = Y0, *Za = Z0, *Yb = Y1, *Zb = Z1;
  for (int it = 0; it < NS_ITERS; it++) {
    ns_t_kernel<<<dim3(8, 8, NM), 256, 0, stream>>>(Za, Ya, T);
    ns_upd_kernel<<<dim3(8, 8, NM * 2), 256, 0, stream>>>(Ya, Za, T, Yb, Zb);
    double* tmp;
    tmp = Ya; Ya = Yb; Yb = tmp;
    tmp = Za; Za = Zb; Zb = tmp;
  }
  finalize_kernel<<<dim3(NB * NC * NC / 256, 3), 256, 0, stream>>>(Ya, Za, scaleArr,
                                                                   inv_c, inv_s, sqr_s);

  // 6: whiten both features, output [p][c] directly
  whiten_kernel<<<dim3(NP / 128, NC / 64, 2 * NB), 256, 0, stream>>>(
      content, style, mean, inv_c, inv_s, ncwT, nswT);

  // 7: fused fp16 split + style ssq (row-wise), then knorm box
  split_kernel<<<dim3(NP / 4, 1, 2 * NB), 256, 0, stream>>>(ncwT, nswT,
                                                            BhiT, BloT, AhiT, AloT, ssq);
  rknorm_kernel<<<NB * NP / 256, 256, 0, stream>>>(ssq, rk);

  // 8-9: per batch: D = A B^T (MFMA fp16 3-term), then shifted-sum score + argmax
  for (int b = 0; b < NB; b++) {
    dmat_kernel<<<dim3(NP / 128, NP / 128), 256, 0, stream>>>(AhiT, AloT, BhiT, BloT, Dbuf, b);
    score_kernel<<<dim3(NP / 256, NSLAB), 256, 0, stream>>>(Dbuf, rk, pbest, pidx, b);
    combine_kernel<<<NP / 256, 256, 0, stream>>>(pbest, pidx, bidx, b);
  }

  // 11: reassembly (gather form) straight from nswT
  reassemble_kernel<<<NB * NP, 256, 0, stream>>>(nswT, bidx, reass);

  // 12: coloring straight into d_out (style_strength == 1.0)
  coloring_kernel<<<dim3(NC / 64, NP / 64, NB), 256, 0, stream>>>(sqr_s, reass, mean, out);
}

// Round 12
// 1145.125 us; speedup vs baseline: 1.1359x; 1.0985x over previous
//
#include <hip/hip_runtime.h>
#include <stdint.h>

// Problem constants
constexpr int NB = 4;      // batch
constexpr int NC = 256;    // channels
constexpr int HW = 64;     // spatial side
constexpr int NP = 4096;   // HW*HW
constexpr int NM = 8;      // matrices for Newton-Schulz: 2 feats x 4 batches
constexpr int NS_ITERS = 7;       // lam_scaled ~0.135 -> residual 4.4e-13 at 7 (fp32 floor 6e-8)
constexpr int NSLAB = 64;         // R2: score occupancy fix
constexpr int PSLAB = NP / NSLAB; // 64
constexpr int KSPLIT = 8;         // cov K-split
constexpr int KCHUNK = NP / KSPLIT; // 512
constexpr int NTILE8 = 36;        // upper-tri 32-tiles in 8x8 grid (R12: NS symmetric)

// fp16 Markidis split (bf16 2-split caused argmax flips). Pre-scale by 512
// keeps lo out of fp16-subnormal range; uniform scaling is argmax-invariant
// for D, and is divided back out for cov.
constexpr float SPLIT_SCALE = 512.0f;
constexpr double COV_DESCALE = 1.0 / ((double)SPLIT_SCALE * (double)SPLIT_SCALE);

typedef __attribute__((ext_vector_type(8))) _Float16 h8v;  // 8 fp16 (4 VGPRs)
typedef __attribute__((ext_vector_type(4))) _Float16 h4v;  // 4 fp16 (8B store)
typedef __attribute__((ext_vector_type(4))) float f4v;     // MFMA acc

// async global->LDS, 16B per lane; lds arg must be wave-uniform
#define GLD16(lds, g)                                                        \
  __builtin_amdgcn_global_load_lds(                                          \
      (const __attribute__((address_space(1))) void*)(g),                    \
      (__attribute__((address_space(3))) void*)(lds), 16, 0, 0)

// ---------------------------------------------------------------------------
// 1. fused mean + raw fp16 split: (src-mu)*512 -> fp16 hi/lo in [c][p]
__global__ __launch_bounds__(256) void meansplit_kernel(const float* __restrict__ content,
                                                        const float* __restrict__ style,
                                                        float* __restrict__ mean,
                                                        _Float16* __restrict__ Czh,
                                                        _Float16* __restrict__ Czl) {
  int id = blockIdx.x;              // [0, 2*NB*NC) == m*NC + c
  int feat = id / (NB * NC);
  int bc = id % (NB * NC);
  const float* src = (feat ? style : content) + (size_t)bc * NP;
  int tid = threadIdx.x;
  float s = 0.f;
  for (int i = tid; i < NP; i += 256) s += src[i];
  __shared__ float red[256];
  red[tid] = s;
  __syncthreads();
  for (int st = 128; st > 0; st >>= 1) {
    if (tid < st) red[tid] += red[tid + st];
    __syncthreads();
  }
  float mu = red[0] * (1.0f / NP);
  if (tid == 0) mean[id] = mu;
  _Float16* oh = Czh + (size_t)id * NP;
  _Float16* ol = Czl + (size_t)id * NP;
  for (int f4 = tid; f4 < NP / 4; f4 += 256) {
    float4 v = *(const float4*)&src[f4 * 4];
    float vv[4] = {v.x, v.y, v.z, v.w};
    h4v h, l;
#pragma unroll
    for (int q = 0; q < 4; q++) {
      float sv = (vv[q] - mu) * SPLIT_SCALE;
      _Float16 hh = (_Float16)sv;
      h[q] = hh;
      l[q] = (_Float16)(sv - (float)hh);
    }
    *(h4v*)&oh[f4 * 4] = h;
    *(h4v*)&ol[f4 * 4] = l;
  }
}

// ---------------------------------------------------------------------------
// 2. MFMA syrk cov: 64x64 upper-tri tiles, 4-term fp16 split, per-32-k fp64 fold
__global__ __launch_bounds__(256) void cov_mfma_kernel(const _Float16* __restrict__ Czh,
                                                       const _Float16* __restrict__ Czl,
                                                       double* __restrict__ pcov) {
  __shared__ _Float16 sAh[64 * 32], sAl[64 * 32], sBh[64 * 32], sBl[64 * 32];
  int m = blockIdx.z;
  int t = blockIdx.x, ti = 0, rem = t;
  while (rem >= 4 - ti) { rem -= 4 - ti; ti++; }
  int tj = ti + rem;
  int i0 = ti * 64, j0 = tj * 64;
  const _Float16* Ah = Czh + ((size_t)m * NC + i0) * NP;
  const _Float16* Al = Czl + ((size_t)m * NC + i0) * NP;
  const _Float16* Bh = Czh + ((size_t)m * NC + j0) * NP;
  const _Float16* Bl = Czl + ((size_t)m * NC + j0) * NP;
  int k0base = blockIdx.y * KCHUNK;
  int tid = threadIdx.x, lane = tid & 63;
  int mm = lane & 15, quad = lane >> 4;
  int w = tid >> 6, qr = w & 1, qc = w >> 1;
  double dacc[2][2][4] = {};
  for (int step = 0; step < KCHUNK / 32; step++) {
    int k0 = k0base + step * 32;
    __syncthreads();
    {
      int row = tid >> 2, koff = (tid & 3) * 8;
      int sbase = (tid & ~63) * 8;   // wave-uniform
      GLD16(&sAh[sbase], Ah + (size_t)row * NP + k0 + koff);
      GLD16(&sAl[sbase], Al + (size_t)row * NP + k0 + koff);
      GLD16(&sBh[sbase], Bh + (size_t)row * NP + k0 + koff);
      GLD16(&sBl[sbase], Bl + (size_t)row * NP + k0 + koff);
    }
    __syncthreads();   // drains vmcnt per barrier semantics
    h8v afh[2], afl[2], bfh[2], bfl[2];
#pragma unroll
    for (int tt = 0; tt < 2; tt++) {
      int ra = (qr * 32 + tt * 16 + mm) * 32 + quad * 8;
      afh[tt] = *(const h8v*)&sAh[ra];
      afl[tt] = *(const h8v*)&sAl[ra];
      int rb = (qc * 32 + tt * 16 + mm) * 32 + quad * 8;
      bfh[tt] = *(const h8v*)&sBh[rb];
      bfl[tt] = *(const h8v*)&sBl[rb];
    }
    f4v acc[2][2] = {};
#pragma unroll
    for (int tr = 0; tr < 2; tr++)
#pragma unroll
      for (int tc = 0; tc < 2; tc++) {
        acc[tr][tc] = __builtin_amdgcn_mfma_f32_16x16x32_f16(afh[tr], bfh[tc], acc[tr][tc], 0, 0, 0);
        acc[tr][tc] = __builtin_amdgcn_mfma_f32_16x16x32_f16(afh[tr], bfl[tc], acc[tr][tc], 0, 0, 0);
        acc[tr][tc] = __builtin_amdgcn_mfma_f32_16x16x32_f16(afl[tr], bfh[tc], acc[tr][tc], 0, 0, 0);
        acc[tr][tc] = __builtin_amdgcn_mfma_f32_16x16x32_f16(afl[tr], bfl[tc], acc[tr][tc], 0, 0, 0);
      }
#pragma unroll
    for (int tr = 0; tr < 2; tr++)
#pragma unroll
      for (int tc = 0; tc < 2; tc++)
#pragma unroll
        for (int r = 0; r < 4; r++) dacc[tr][tc][r] += (double)acc[tr][tc][r];
  }
  double* dst = pcov + ((size_t)blockIdx.y * NM + m) * NC * NC;
  // C/D layout: col = lane&15, row = quad*4 + reg  [verified mapping]
#pragma unroll
  for (int tr = 0; tr < 2; tr++)
#pragma unroll
    for (int tc = 0; tc < 2; tc++)
#pragma unroll
      for (int r = 0; r < 4; r++) {
        int row = i0 + qr * 32 + tr * 16 + quad * 4 + r;
        int col = j0 + qc * 32 + tc * 16 + mm;
        dst[(size_t)row * NC + col] = dacc[tr][tc][r];
      }
}

// 2b. sum K-split partials; mirror lower triangle from upper tiles; descale
__global__ __launch_bounds__(256) void cov_reduce_kernel(const double* __restrict__ pcov,
                                                         double* __restrict__ cov) {
  size_t idx = (size_t)blockIdx.x * 256 + threadIdx.x;  // [0, NM*NC*NC)
  int m = (int)(idx >> 16);
  int ij = (int)(idx & 65535);
  int i = ij >> 8, j = ij & 255;
  int src = ((i >> 6) <= (j >> 6)) ? ij : ((j << 8) | i);
  double s = 0;
  for (int k = 0; k < KSPLIT; k++)
    s += pcov[((size_t)k * NM + m) * 65536 + src];
  cov[idx] = s * COV_DESCALE;
}

// ---------------------------------------------------------------------------
// 3. Gershgorin bound (abs row sum, A symmetric); init Y = s*A, Z = I
__global__ __launch_bounds__(256) void bound_init_kernel(const double* __restrict__ cov,
                                                         double* __restrict__ Y,
                                                         double* __restrict__ Z,
                                                         double* __restrict__ scaleArr) {
  int m = blockIdx.x;
  const double* A = cov + (size_t)m * NC * NC;
  int t = threadIdx.x;
  double s = 0;
  for (int i = 0; i < NC; i++) s += fabs(A[(size_t)i * NC + t]);   // coalesced
  __shared__ double red[256];
  red[t] = s;
  __syncthreads();
  for (int st = 128; st > 0; st >>= 1) {
    if (t < st) red[t] = fmax(red[t], red[t + st]);
    __syncthreads();
  }
  double scale = 1.0 / red[0];     // lam_max <= max abs row sum (rigorous upper bound)
  if (t == 0) scaleArr[m] = scale;
  double* Ym = Y + (size_t)m * NC * NC;
  double* Zm = Z + (size_t)m * NC * NC;
  for (int idx = t; idx < NC * NC; idx += 256) {
    Ym[idx] = A[idx] * scale;
    Zm[idx] = ((idx / NC) == (idx % NC)) ? 1.0 : 0.0;
  }
}

// ---------------------------------------------------------------------------
// R12: NS iterates are polynomials in symmetric A -> Y, Z, T, Y*T, T*Z all
// symmetric. Compute only the 36/64 upper-tri 32x32 tiles and mirror-write
// the lower tile (coalesced via LDS transpose). ~44% of NS GEMM work removed,
// numerics identical up to ulp-level forced symmetry.

// 4a. T = Z * Y (fp64, upper-tri 32x32 tiles, 2x2 micro, mirrored writes)
__global__ __launch_bounds__(256) void ns_t_kernel(const double* __restrict__ Zin,
                                                   const double* __restrict__ Yin,
                                                   double* __restrict__ T) {
  int m = blockIdx.z;
  const double* Am = Zin + (size_t)m * NC * NC;
  const double* Bm = Yin + (size_t)m * NC * NC;
  double* Tm = T + (size_t)m * NC * NC;
  __shared__ double As[32][33];
  __shared__ double Bs[32][33];
  int tid = threadIdx.x, tx = tid & 15, ty = tid >> 4;
  int t = blockIdx.x, ti = 0, rem = t;     // unrank upper-tri tile (8x8 grid)
  while (rem >= 8 - ti) { rem -= 8 - ti; ti++; }
  int tj = ti + rem;
  int i0 = ti * 32, j0 = tj * 32;
  double a00 = 0, a01 = 0, a10 = 0, a11 = 0;
  for (int k0 = 0; k0 < NC; k0 += 32) {
    for (int idx = tid; idx < 1024; idx += 256) {
      int r = idx >> 5, cc = idx & 31;
      As[r][cc] = Am[(size_t)(i0 + r) * NC + k0 + cc];
      Bs[r][cc] = Bm[(size_t)(k0 + r) * NC + j0 + cc];
    }
    __syncthreads();
#pragma unroll
    for (int kk = 0; kk < 32; kk++) {
      double x0 = As[ty * 2][kk], x1 = As[ty * 2 + 1][kk];
      double y0 = Bs[kk][tx * 2], y1 = Bs[kk][tx * 2 + 1];
      a00 += x0 * y0; a01 += x0 * y1; a10 += x1 * y0; a11 += x1 * y1;
    }
    __syncthreads();
  }
  Tm[(size_t)(i0 + ty * 2) * NC + j0 + tx * 2] = a00;
  Tm[(size_t)(i0 + ty * 2) * NC + j0 + tx * 2 + 1] = a01;
  Tm[(size_t)(i0 + ty * 2 + 1) * NC + j0 + tx * 2] = a10;
  Tm[(size_t)(i0 + ty * 2 + 1) * NC + j0 + tx * 2 + 1] = a11;
  if (ti != tj) {   // mirror tile, coalesced via LDS transpose (reuse As)
    As[ty * 2][tx * 2] = a00;
    As[ty * 2][tx * 2 + 1] = a01;
    As[ty * 2 + 1][tx * 2] = a10;
    As[ty * 2 + 1][tx * 2 + 1] = a11;
    __syncthreads();
    for (int idx = tid; idx < 1024; idx += 256) {
      int r = idx >> 5, cc = idx & 31;
      Tm[(size_t)(j0 + r) * NC + i0 + cc] = As[cc][r];
    }
  }
}

// 4b. Yout = 1.5*Yin - 0.5*Yin*T ; Zout = 1.5*Zin - 0.5*T*Zin
//     (upper-tri tiles + mirror; Y*T = Y*Z*Y and T*Z = Z*Y*Z are symmetric)
__global__ __launch_bounds__(256) void ns_upd_kernel(const double* __restrict__ Yin,
                                                     const double* __restrict__ Zin,
                                                     const double* __restrict__ T,
                                                     double* __restrict__ Yout,
                                                     double* __restrict__ Zout) {
  int z = blockIdx.z;
  int m = z & 7, which = z >> 3;
  size_t off = (size_t)m * NC * NC;
  const double* Am = which == 0 ? (Yin + off) : (T + off);
  const double* Bm = which == 0 ? (T + off) : (Zin + off);
  const double* Sm = which == 0 ? (Yin + off) : (Zin + off);
  double* Om = which == 0 ? (Yout + off) : (Zout + off);
  __shared__ double As[32][33];
  __shared__ double Bs[32][33];
  int tid = threadIdx.x, tx = tid & 15, ty = tid >> 4;
  int t = blockIdx.x, ti = 0, rem = t;     // unrank upper-tri tile (8x8 grid)
  while (rem >= 8 - ti) { rem -= 8 - ti; ti++; }
  int tj = ti + rem;
  int i0 = ti * 32, j0 = tj * 32;
  double a00 = 0, a01 = 0, a10 = 0, a11 = 0;
  for (int k0 = 0; k0 < NC; k0 += 32) {
    for (int idx = tid; idx < 1024; idx += 256) {
      int r = idx >> 5, cc = idx & 31;
      As[r][cc] = Am[(size_t)(i0 + r) * NC + k0 + cc];
      Bs[r][cc] = Bm[(size_t)(k0 + r) * NC + j0 + cc];
    }
    __syncthreads();
#pragma unroll
    for (int kk = 0; kk < 32; kk++) {
      double x0 = As[ty * 2][kk], x1 = As[ty * 2 + 1][kk];
      double y0 = Bs[kk][tx * 2], y1 = Bs[kk][tx * 2 + 1];
      a00 += x0 * y0; a01 += x0 * y1; a10 += x1 * y0; a11 += x1 * y1;
    }
    __syncthreads();
  }
  int r0 = i0 + ty * 2, c0 = j0 + tx * 2;
  double o00 = 1.5 * Sm[(size_t)r0 * NC + c0] - 0.5 * a00;
  double o01 = 1.5 * Sm[(size_t)r0 * NC + c0 + 1] - 0.5 * a01;
  double o10 = 1.5 * Sm[(size_t)(r0 + 1) * NC + c0] - 0.5 * a10;
  double o11 = 1.5 * Sm[(size_t)(r0 + 1) * NC + c0 + 1] - 0.5 * a11;
  Om[(size_t)r0 * NC + c0] = o00;
  Om[(size_t)r0 * NC + c0 + 1] = o01;
  Om[(size_t)(r0 + 1) * NC + c0] = o10;
  Om[(size_t)(r0 + 1) * NC + c0 + 1] = o11;
  if (ti != tj) {   // mirror tile via LDS transpose (reuse As)
    As[ty * 2][tx * 2] = o00;
    As[ty * 2][tx * 2 + 1] = o01;
    As[ty * 2 + 1][tx * 2] = o10;
    As[ty * 2 + 1][tx * 2 + 1] = o11;
    __syncthreads();
    for (int idx = tid; idx < 1024; idx += 256) {
      int r = idx >> 5, cc = idx & 31;
      Om[(size_t)(j0 + r) * NC + i0 + cc] = As[cc][r];
    }
  }
}

// ---------------------------------------------------------------------------
// 5. finalize: inv_c = Z_c*sqrt(s), inv_s = Z_s*sqrt(s), sqr_s = Y_s/sqrt(s)  (fp32)
__global__ __launch_bounds__(256) void finalize_kernel(const double* __restrict__ Yf,
                                                       const double* __restrict__ Zf,
                                                       const double* __restrict__ scaleArr,
                                                       float* __restrict__ inv_c,
                                                       float* __restrict__ inv_s,
                                                       float* __restrict__ sqr_s) {
  int which = blockIdx.y;
  int idx = blockIdx.x * 256 + threadIdx.x;   // [0, NB*NC*NC)
  int b = idx >> 16;
  int ij = idx & 65535;
  if (which == 0) {
    double s = sqrt(scaleArr[b]);
    inv_c[idx] = (float)(Zf[(size_t)b * 65536 + ij] * s);
  } else if (which == 1) {
    double s = sqrt(scaleArr[4 + b]);
    inv_s[idx] = (float)(Zf[(size_t)(4 + b) * 65536 + ij] * s);
  } else {
    double s = sqrt(scaleArr[4 + b]);
    sqr_s[idx] = (float)(Yf[(size_t)(4 + b) * 65536 + ij] / s);
  }
}

// ---------------------------------------------------------------------------
// 6. whitening: outT[x][c] = sum_k (src[k][x]-mu[k]) * M[k][c]. Emits [p][c]
//    directly. M symmetric -> Ms[k][c] staged from M rows (float4, conflict-free).
__global__ __launch_bounds__(256) void whiten_kernel(const float* __restrict__ content,
                                                     const float* __restrict__ style,
                                                     const float* __restrict__ mean,
                                                     const float* __restrict__ inv_c,
                                                     const float* __restrict__ inv_s,
                                                     float* __restrict__ ncwT,
                                                     float* __restrict__ nswT) {
  int z = blockIdx.z; int feat = z >> 2, b = z & 3;
  const float* src = (feat ? style : content) + (size_t)b * NC * NP;
  const float* mu = mean + (size_t)feat * NB * NC + b * NC;
  const float* M = (feat ? inv_s : inv_c) + (size_t)b * NC * NC;
  float* dst = (feat ? nswT : ncwT) + (size_t)b * NP * NC;   // [p][c]
  int x0 = blockIdx.x * 128, c0 = blockIdx.y * 64;
  __shared__ float Ms[32][68];    // [k][c]
  __shared__ float Xs[32][136];   // [k][x]
  int tid = threadIdx.x, tx = tid & 15, ty = tid >> 4;
  float acc[8][4] = {};   // [x_i][c_j]
  for (int k0 = 0; k0 < NC; k0 += 32) {
    for (int idx = tid; idx < 512; idx += 256) {
      int kk = idx >> 4, r4 = (idx & 15) * 4;
      *(float4*)&Ms[kk][r4] = *(const float4*)&M[(size_t)(k0 + kk) * NC + c0 + r4];
    }
    for (int idx = tid; idx < 1024; idx += 256) {
      int r = idx >> 5, c4 = (idx & 31) * 4;
      float4 v = *(const float4*)&src[(size_t)(k0 + r) * NP + x0 + c4];
      float mm = mu[k0 + r];
      v.x -= mm; v.y -= mm; v.z -= mm; v.w -= mm;
      *(float4*)&Xs[r][c4] = v;
    }
    __syncthreads();
#pragma unroll
    for (int kk = 0; kk < 32; kk++) {
      float4 xa = *(const float4*)&Xs[kk][ty * 8];
      float4 xb = *(const float4*)&Xs[kk][ty * 8 + 4];
      float4 mv = *(const float4*)&Ms[kk][tx * 4];
      float xv[8] = {xa.x, xa.y, xa.z, xa.w, xb.x, xb.y, xb.z, xb.w};
      float mm4[4] = {mv.x, mv.y, mv.z, mv.w};
#pragma unroll
      for (int i = 0; i < 8; i++)
#pragma unroll
        for (int j = 0; j < 4; j++) acc[i][j] += xv[i] * mm4[j];
    }
    __syncthreads();
  }
#pragma unroll
  for (int i = 0; i < 8; i++)
    *(float4*)&dst[(size_t)(x0 + ty * 8 + i) * NC + c0 + tx * 4] =
        make_float4(acc[i][0], acc[i][1], acc[i][2], acc[i][3]);
}

// ---------------------------------------------------------------------------
// 7. fused row-wise fp16 Markidis split + style ssq (one wave per row y)
__global__ __launch_bounds__(256) void split_kernel(const float* __restrict__ ncwT,
                                                    const float* __restrict__ nswT,
                                                    _Float16* __restrict__ BhiT,
                                                    _Float16* __restrict__ BloT,
                                                    _Float16* __restrict__ AhiT,
                                                    _Float16* __restrict__ AloT,
                                                    float* __restrict__ ssq) {
  int z = blockIdx.z; int feat = z >> 2, b = z & 3;
  int wave = threadIdx.x >> 6, lane = threadIdx.x & 63;
  int y = blockIdx.x * 4 + wave;
  const float* src = (feat ? nswT : ncwT) + ((size_t)b * NP + y) * NC;
  _Float16* oh = (feat ? AhiT : BhiT) + ((size_t)b * NP + y) * NC;
  _Float16* ol = (feat ? AloT : BloT) + ((size_t)b * NP + y) * NC;
  float4 v = *(const float4*)&src[lane * 4];
  float vv[4] = {v.x, v.y, v.z, v.w};
  h4v h, l;
#pragma unroll
  for (int q = 0; q < 4; q++) {
    float sv = vv[q] * SPLIT_SCALE;
    _Float16 hh = (_Float16)sv;          // v_cvt_f16_f32, RTN
    h[q] = hh;
    l[q] = (_Float16)(sv - (float)hh);
  }
  *(h4v*)&oh[lane * 4] = h;
  *(h4v*)&ol[lane * 4] = l;
  if (feat) {
    float s = vv[0] * vv[0] + vv[1] * vv[1] + vv[2] * vv[2] + vv[3] * vv[3];
#pragma unroll
    for (int off = 32; off > 0; off >>= 1) s += __shfl_down(s, off);
    if (lane == 0) ssq[b * NP + y] = s;
  }
}

__global__ __launch_bounds__(256) void rknorm_kernel(const float* __restrict__ ssq,
                                                     float* __restrict__ rk) {
  int idx = blockIdx.x * 256 + threadIdx.x;
  int b = idx >> 12, p = idx & 4095;
  int pi = p >> 6, pj = p & 63;
  float s = 0.f;
#pragma unroll
  for (int d = -1; d <= 1; d++)
#pragma unroll
    for (int e = -1; e <= 1; e++) {
      if ((unsigned)(pi + d) < 64u && (unsigned)(pj + e) < 64u)
        s += ssq[b * NP + (pi + d) * 64 + pj + e];
    }
  rk[idx] = 1.0f / sqrtf(s);
}

// ---------------------------------------------------------------------------
// 8. MFMA: D[p][x] = sum_c A[p][c]*B[x][c] via 3-term fp16 split (hh, hl, lh).
//    128x128 tile/block, 4 waves each 64x64 (4x4 of mfma_f32_16x16x32_f16),
//    BK=32, global_load_lds 16B staging.
__global__ __launch_bounds__(256) void dmat_kernel(const _Float16* __restrict__ AhiT,
                                                   const _Float16* __restrict__ AloT,
                                                   const _Float16* __restrict__ BhiT,
                                                   const _Float16* __restrict__ BloT,
                                                   float* __restrict__ D, int b) {
  __shared__ _Float16 sAh[128 * 32], sAl[128 * 32], sBh[128 * 32], sBl[128 * 32];
  const _Float16* Ah = AhiT + (size_t)b * NP * NC;
  const _Float16* Al = AloT + (size_t)b * NP * NC;
  const _Float16* Bh = BhiT + (size_t)b * NP * NC;
  const _Float16* Bl = BloT + (size_t)b * NP * NC;
  int p0 = blockIdx.x * 128, x0 = blockIdx.y * 128;
  int tid = threadIdx.x, lane = tid & 63;
  int m = lane & 15, quad = lane >> 4;
  int w = tid >> 6, qr = w & 1, qc = w >> 1;
  f4v acc[4][4] = {};
  for (int step = 0; step < NC / 32; step++) {
    int c0 = step * 32;
    __syncthreads();
#pragma unroll
    for (int i = 0; i < 2; i++) {
      int seg = i * 256 + tid;
      int row = seg >> 2, koff = (seg & 3) * 8;
      int sbase = (i * 256 + (tid & ~63)) * 8;   // wave-uniform
      GLD16(&sAh[sbase], Ah + (size_t)(p0 + row) * NC + c0 + koff);
      GLD16(&sAl[sbase], Al + (size_t)(p0 + row) * NC + c0 + koff);
      GLD16(&sBh[sbase], Bh + (size_t)(x0 + row) * NC + c0 + koff);
      GLD16(&sBl[sbase], Bl + (size_t)(x0 + row) * NC + c0 + koff);
    }
    __syncthreads();   // drains vmcnt (global_load_lds) per barrier semantics
    h8v afh[4], afl[4], bfh[4], bfl[4];
#pragma unroll
    for (int t = 0; t < 4; t++) {
      int ra = (qr * 64 + t * 16 + m) * 32 + quad * 8;
      afh[t] = *(const h8v*)&sAh[ra];
      afl[t] = *(const h8v*)&sAl[ra];
      int rb = (qc * 64 + t * 16 + m) * 32 + quad * 8;
      bfh[t] = *(const h8v*)&sBh[rb];
      bfl[t] = *(const h8v*)&sBl[rb];
    }
#pragma unroll
    for (int tr = 0; tr < 4; tr++)
#pragma unroll
      for (int tc = 0; tc < 4; tc++) {
        acc[tr][tc] = __builtin_amdgcn_mfma_f32_16x16x32_f16(afh[tr], bfh[tc], acc[tr][tc], 0, 0, 0);
        acc[tr][tc] = __builtin_amdgcn_mfma_f32_16x16x32_f16(afh[tr], bfl[tc], acc[tr][tc], 0, 0, 0);
        acc[tr][tc] = __builtin_amdgcn_mfma_f32_16x16x32_f16(afl[tr], bfh[tc], acc[tr][tc], 0, 0, 0);
      }
  }
  // C/D layout: col = lane&15, row = quad*4 + reg  [verified mapping]
#pragma unroll
  for (int tr = 0; tr < 4; tr++)
#pragma unroll
    for (int tc = 0; tc < 4; tc++)
#pragma unroll
      for (int r = 0; r < 4; r++) {
        int row = p0 + qr * 64 + tr * 16 + quad * 4 + r;
        int col = x0 + qc * 64 + tc * 16 + m;
        D[(size_t)row * NP + col] = acc[tr][tc][r];
      }
}

// ---------------------------------------------------------------------------
// 9. score[p][x] = (sum_{3x3 masked} D[p+off][x+off]) * rk[p]; partial argmax per p-slab
__global__ __launch_bounds__(256) void score_kernel(const float* __restrict__ D,
                                                    const float* __restrict__ rk,
                                                    float* __restrict__ pbest,
                                                    int* __restrict__ pidx, int b) {
  int x = blockIdx.x * 256 + threadIdx.x;
  int slab = blockIdx.y;
  int xi = x >> 6, xj = x & 63;
  const float* rkb = rk + (size_t)b * NP;
  bool xm[9];
#pragma unroll
  for (int q = 0; q < 9; q++) {
    int d = q / 3 - 1, e = q % 3 - 1;
    xm[q] = ((unsigned)(xi + d) < 64u) && ((unsigned)(xj + e) < 64u);
  }
  float best = -1e30f;
  int bi = 0;
  int p0 = slab * PSLAB;
  for (int p = p0; p < p0 + PSLAB; p++) {
    int pi = p >> 6, pj = p & 63;
    float acc = 0.f;
#pragma unroll
    for (int q = 0; q < 9; q++) {
      int d = q / 3 - 1, e = q % 3 - 1;
      int off = d * 64 + e;
      bool ok = xm[q] && ((unsigned)(pi + d) < 64u) && ((unsigned)(pj + e) < 64u);
      int row = ok ? p + off : p;
      int col = ok ? x + off : x;
      float t = D[(size_t)row * NP + col];
      acc += ok ? t : 0.f;
    }
    float s = acc * rkb[p];
    if (s > best) { best = s; bi = p; }
  }
  pbest[slab * NP + x] = best;
  pidx[slab * NP + x] = bi;
}

__global__ __launch_bounds__(256) void combine_kernel(const float* __restrict__ pbest,
                                                      const int* __restrict__ pidx,
                                                      int* __restrict__ bidx, int b) {
  int x = blockIdx.x * 256 + threadIdx.x;
  float best = pbest[x];
  int bi = pidx[x];
  for (int s = 1; s < NSLAB; s++) {
    float v = pbest[s * NP + x];
    if (v > best) { best = v; bi = pidx[s * NP + x]; }
  }
  bidx[b * NP + x] = bi;
}

// ---------------------------------------------------------------------------
// 11. gather-form overlap-add reassembly, divided by deconv norm (reads nswT [p][c])
__global__ __launch_bounds__(256) void reassemble_kernel(const float* __restrict__ nswT,
                                                         const int* __restrict__ bidx,
                                                         float* __restrict__ reass) {
  int by = blockIdx.x;       // b*NP + y
  int b = by >> 12, y = by & 4095;
  int yi = y >> 6, yj = y & 63;
  int t = threadIdx.x;       // channel
  float acc = 0.f;
#pragma unroll
  for (int oi = 0; oi < 3; oi++)
#pragma unroll
    for (int oj = 0; oj < 3; oj++) {
      int xi = yi + 1 - oi, xj = yj + 1 - oj;
      if ((unsigned)xi < 64u && (unsigned)xj < 64u) {
        int p = bidx[b * NP + xi * 64 + xj];
        int qi = (p >> 6) + oi - 1, qj = (p & 63) + oj - 1;
        if ((unsigned)qi < 64u && (unsigned)qj < 64u)
          acc += nswT[((size_t)b * NP + qi * 64 + qj) * NC + t];
      }
    }
  int cy = (yi == 0 || yi == 63) ? 2 : 3;
  int cx = (yj == 0 || yj == 63) ? 2 : 3;
  reass[((size_t)b * NP + y) * NC + t] = acc / (float)(cy * cx);
}

// ---------------------------------------------------------------------------
// 12. coloring: out[b][c][y] = sum_j sqr_s[b][c][j]*reass[b][y][j] + mean_s[b][c].
//     sqr_s symmetric -> As staged from rows (float4, conflict-free).
__global__ __launch_bounds__(256) void coloring_kernel(const float* __restrict__ sqr_s,
                                                       const float* __restrict__ reass,
                                                       const float* __restrict__ mean,
                                                       float* __restrict__ out) {
  int b = blockIdx.z;
  const float* A = sqr_s + (size_t)b * NC * NC;
  const float* Bm = reass + (size_t)b * NP * NC;
  const float* mu = mean + (size_t)NB * NC + b * NC;
  float* dst = out + (size_t)b * NC * NP;
  int c0 = blockIdx.x * 64, y0 = blockIdx.y * 64;
  __shared__ float As[32][68];   // [j][c], float4 rows
  __shared__ float Bs[32][66];   // [j][y], transposed scalar writes
  int tid = threadIdx.x, tx = tid & 15, ty = tid >> 4;
  float acc[4][4] = {};
  for (int k0 = 0; k0 < NC; k0 += 32) {
    for (int idx = tid; idx < 512; idx += 256) {
      int kk = idx >> 4, r4 = (idx & 15) * 4;   // A symmetric: row k, cols c
      *(float4*)&As[kk][r4] = *(const float4*)&A[(size_t)(k0 + kk) * NC + c0 + r4];
    }
    for (int idx = tid; idx < 2048; idx += 256) {
      int r = idx >> 5, kk = idx & 31;
      Bs[kk][r] = Bm[(size_t)(y0 + r) * NC + k0 + kk];
    }
    __syncthreads();
#pragma unroll
    for (int kk = 0; kk < 32; kk++) {
      float4 av = *(const float4*)&As[kk][ty * 4];
      float a[4] = {av.x, av.y, av.z, av.w};
      float bb[4];
      *(float2*)&bb[0] = *(const float2*)&Bs[kk][tx * 4];
      *(float2*)&bb[2] = *(const float2*)&Bs[kk][tx * 4 + 2];
#pragma unroll
      for (int i = 0; i < 4; i++)
#pragma unroll
        for (int j = 0; j < 4; j++) acc[i][j] += a[i] * bb[j];
    }
    __syncthreads();
  }
#pragma unroll
  for (int i = 0; i < 4; i++) {
    float m = mu[c0 + ty * 4 + i];
    float4 v = make_float4(acc[i][0] + m, acc[i][1] + m, acc[i][2] + m, acc[i][3] + m);
    *(float4*)&dst[(size_t)(c0 + ty * 4 + i) * NP + y0 + tx * 4] = v;
  }
}

// ---------------------------------------------------------------------------
extern "C" void kernel_launch(void* const* d_in, const int* in_sizes, int n_in,
                              void* d_out, int out_size, void* d_ws, size_t ws_size,
                              hipStream_t stream) {
  (void)in_sizes; (void)n_in; (void)out_size; (void)ws_size;
  const float* content = (const float*)d_in[0];
  const float* style = (const float*)d_in[1];
  float* out = (float*)d_out;

  // workspace carve-up (256B aligned)
  char* w = (char*)d_ws;
  auto alloc = [&](size_t bytes) -> void* {
    void* p = (void*)w;
    w += (bytes + 255) & ~(size_t)255;
    return p;
  };
  float* mean = (float*)alloc(2 * NB * NC * sizeof(float));
  double* pcov = (double*)alloc((size_t)KSPLIT * NM * NC * NC * sizeof(double));  // 32MB
  double* cov = (double*)alloc((size_t)NM * NC * NC * sizeof(double));
  double* Y0 = (double*)alloc((size_t)NM * NC * NC * sizeof(double));
  double* Z0 = (double*)alloc((size_t)NM * NC * NC * sizeof(double));
  double* Y1 = (double*)alloc((size_t)NM * NC * NC * sizeof(double));
  double* Z1 = (double*)alloc((size_t)NM * NC * NC * sizeof(double));
  double* T = (double*)alloc((size_t)NM * NC * NC * sizeof(double));
  double* scaleArr = (double*)alloc(NM * sizeof(double));
  float* inv_c = (float*)alloc((size_t)NB * NC * NC * sizeof(float));
  float* inv_s = (float*)alloc((size_t)NB * NC * NC * sizeof(float));
  float* sqr_s = (float*)alloc((size_t)NB * NC * NC * sizeof(float));
  float* ncwT = (float*)alloc((size_t)NB * NP * NC * sizeof(float));  // [p][c]
  float* nswT = (float*)alloc((size_t)NB * NP * NC * sizeof(float));  // [p][c]
  float* ssq = (float*)alloc((size_t)NB * NP * sizeof(float));
  float* rk = (float*)alloc((size_t)NB * NP * sizeof(float));
  float* pbest = (float*)alloc((size_t)NSLAB * NP * sizeof(float));
  int* pidx = (int*)alloc((size_t)NSLAB * NP * sizeof(int));
  int* bidx = (int*)alloc((size_t)NB * NP * sizeof(int));
  float* Dbuf = (float*)alloc((size_t)NP * NP * sizeof(float));  // 64MB, multi-overlaid:
  float* reass = Dbuf + (size_t)NB * NP * NC;          // [16MB, 32MB), used after score loop
  // raw fp16 split overlays Dbuf[0,32MB) — dead before dmat first writes Dbuf
  _Float16* Czh = (_Float16*)Dbuf;                       // 16MB: NM*NC*NP fp16
  _Float16* Czl = Czh + (size_t)NM * NC * NP;            // 16MB
  // whitened fp16 split arrays overlay pcov (dead after cov_reduce): 4 x 8MB
  _Float16* AhiT = (_Float16*)pcov;
  _Float16* AloT = AhiT + (size_t)NB * NP * NC;
  _Float16* BhiT = AloT + (size_t)NB * NP * NC;
  _Float16* BloT = BhiT + (size_t)NB * NP * NC;

  // 1-2: fused mean + raw split, then MFMA syrk cov
  meansplit_kernel<<<2 * NB * NC, 256, 0, stream>>>(content, style, mean, Czh, Czl);
  cov_mfma_kernel<<<dim3(10, KSPLIT, NM), 256, 0, stream>>>(Czh, Czl, pcov);
  cov_reduce_kernel<<<NM * NC * NC / 256, 256, 0, stream>>>(pcov, cov);

  // 3-4: Newton-Schulz inverse/forward sqrt in fp64 (Gershgorin-scaled,
  //      R12: symmetric upper-tri tiles only, 36/64 of the GEMM work)
  bound_init_kernel<<<NM, 256, 0, stream>>>(cov, Y0, Z0, scaleArr);
  double *Ya = Y0, *Za = Z0, *Yb = Y1, *Zb = Z1;
  for (int it = 0; it < NS_ITERS; it++) {
    ns_t_kernel<<<dim3(NTILE8, 1, NM), 256, 0, stream>>>(Za, Ya, T);
    ns_upd_kernel<<<dim3(NTILE8, 1, NM * 2), 256, 0, stream>>>(Ya, Za, T, Yb, Zb);
    double* tmp;
    tmp = Ya; Ya = Yb; Yb = tmp;
    tmp = Za; Za = Zb; Zb = tmp;
  }
  finalize_kernel<<<dim3(NB * NC * NC / 256, 3), 256, 0, stream>>>(Ya, Za, scaleArr,
                                                                   inv_c, inv_s, sqr_s);

  // 6: whiten both features, output [p][c] directly
  whiten_kernel<<<dim3(NP / 128, NC / 64, 2 * NB), 256, 0, stream>>>(
      content, style, mean, inv_c, inv_s, ncwT, nswT);

  // 7: fused fp16 split + style ssq (row-wise), then knorm box
  split_kernel<<<dim3(NP / 4, 1, 2 * NB), 256, 0, stream>>>(ncwT, nswT,
                                                            BhiT, BloT, AhiT, AloT, ssq);
  rknorm_kernel<<<NB * NP / 256, 256, 0, stream>>>(ssq, rk);

  // 8-9: per batch: D = A B^T (MFMA fp16 3-term), then shifted-sum score + argmax
  for (int b = 0; b < NB; b++) {
    dmat_kernel<<<dim3(NP / 128, NP / 128), 256, 0, stream>>>(AhiT, AloT, BhiT, BloT, Dbuf, b);
    score_kernel<<<dim3(NP / 256, NSLAB), 256, 0, stream>>>(Dbuf, rk, pbest, pidx, b);
    combine_kernel<<<NP / 256, 256, 0, stream>>>(pbest, pidx, bidx, b);
  }

  // 11: reassembly (gather form) straight from nswT
  reassemble_kernel<<<NB * NP, 256, 0, stream>>>(nswT, bidx, reass);

  // 12: coloring straight into d_out (style_strength == 1.0)
  coloring_kernel<<<dim3(NC / 64, NP / 64, NB), 256, 0, stream>>>(sqr_s, reass, mean, out);
}